// Round 1
// baseline (545.250 us; speedup 1.0000x reference)
//
#include <hip/hip_runtime.h>
#include <math.h>

// Problem constants
#define NB 4
#define NC 64
#define NPTS 4096
#define NK 16
#define NROWS (NB*NPTS)      // 16384
#define NCHUNK 8             // KNN candidate chunks
#define CHSZ (NPTS/NCHUNK)   // 512
#define WT_PSTR 648          // LDS stride per point for wt tile [16][32][20]+pad

// ---------------- top-16 insertion (sorted ascending, dd[15]=max) -------------
__device__ __forceinline__ void insert16(double dist, int j, double (&dd)[16], int (&ii)[16]) {
  double cd = dist; int ci = j;
#pragma unroll
  for (int s = 0; s < 16; ++s) {
    double od = dd[s]; int oi = ii[s];
    bool c = cd < od;
    dd[s] = c ? cd : od;
    ii[s] = c ? ci : oi;
    cd = c ? od : cd;
    ci = c ? oi : ci;
  }
}

__device__ __forceinline__ void wave_reduce_atomic(double v, double* dst) {
#pragma unroll
  for (int off = 32; off; off >>= 1) v += __shfl_down(v, off, 64);
  if ((threadIdx.x & 63) == 0) atomicAdd(dst, v);
}

// ---------------- Kernel 1: partial KNN over candidate chunk ------------------
__global__ __launch_bounds__(256) void knn_partial(const float* __restrict__ pos,
                                                   int* __restrict__ pi) {
  __shared__ float cx[CHSZ], cy[CHSZ], cz[CHSZ];
  int t = threadIdx.x;
  int row0 = blockIdx.x * 256;
  int b = row0 >> 12;
  int j0 = blockIdx.y * CHSZ;
  const float* pb = pos + b * 3 * NPTS;
  for (int i = t; i < CHSZ; i += 256) {
    cx[i] = pb[j0 + i];
    cy[i] = pb[NPTS + j0 + i];
    cz[i] = pb[2 * NPTS + j0 + i];
  }
  __syncthreads();
  int n = (row0 + t) & (NPTS - 1);
  double xi = pb[n], yi = pb[NPTS + n], zi = pb[2 * NPTS + n];
  double dd[16]; int ii[16];
#pragma unroll
  for (int s = 0; s < 16; ++s) { dd[s] = 1e300; ii[s] = 0; }
#pragma unroll 2
  for (int jj = 0; jj < CHSZ; ++jj) {
    double dx = xi - (double)cx[jj];
    double dy = yi - (double)cy[jj];
    double dz = zi - (double)cz[jj];
    double dist = dx * dx + dy * dy + dz * dz;
    if (dist < dd[15]) insert16(dist, j0 + jj, dd, ii);
  }
  int* po = pi + ((size_t)blockIdx.y * NROWS + row0 + t) * 16;
#pragma unroll
  for (int s = 0; s < 16; ++s) po[s] = ii[s];
}

// ------- Kernel 2: merge partials (exact f64 re-rank), gather, BN stats -------
__global__ __launch_bounds__(256) void merge_stats(const float* __restrict__ pos,
                                                   const float* __restrict__ invd,
                                                   const int* __restrict__ pi,
                                                   int* __restrict__ nn_idx,
                                                   float* __restrict__ xbuf,
                                                   double* __restrict__ st) {
  int r = blockIdx.x * blockDim.x + threadIdx.x;
  int b = r >> 12, n = r & (NPTS - 1);
  const float* pb = pos + b * 3 * NPTS;
  double xi = pb[n], yi = pb[NPTS + n], zi = pb[2 * NPTS + n];
  double dd[16]; int ii[16];
#pragma unroll
  for (int s = 0; s < 16; ++s) { dd[s] = 1e300; ii[s] = 0; }
  for (int c = 0; c < NCHUNK; ++c) {
    const int* ps = pi + ((size_t)c * NROWS + r) * 16;
#pragma unroll
    for (int s = 0; s < 16; ++s) {
      int j = ps[s];
      double dx = xi - (double)pb[j];
      double dy = yi - (double)pb[NPTS + j];
      double dz = zi - (double)pb[2 * NPTS + j];
      double dist = dx * dx + dy * dy + dz * dz;
      if (dist < dd[15]) insert16(dist, j, dd, ii);
    }
  }
  // write final indices; gather inverse density
  const float* ivb = invd + b * NPTS;
  float xv[16];
  float vmax = -1e30f;
#pragma unroll
  for (int s = 0; s < 16; ++s) {
    int j = ii[s];
    nn_idx[(size_t)r * 16 + s] = j;
    float v = ivb[j];
    xv[s] = v;
    vmax = fmaxf(vmax, v);
  }
  double sx = 0, sxx = 0;
  double l1x = 0, l1y = 0, l1z = 0;
  double lxx = 0, lyy = 0, lzz = 0, lxy = 0, lxz = 0, lyz = 0;
#pragma unroll
  for (int s = 0; s < 16; ++s) {
    float x = xv[s] / vmax;
    xbuf[(size_t)r * 16 + s] = x;
    sx += x; sxx += (double)x * (double)x;
    int j = ii[s];
    double lx = (double)pb[j] - xi;
    double ly = (double)pb[NPTS + j] - yi;
    double lz = (double)pb[2 * NPTS + j] - zi;
    l1x += lx; l1y += ly; l1z += lz;
    lxx += lx * lx; lyy += ly * ly; lzz += lz * lz;
    lxy += lx * ly; lxz += lx * lz; lyz += ly * lz;
  }
  wave_reduce_atomic(sx, st + 0);
  wave_reduce_atomic(sxx, st + 1);
  wave_reduce_atomic(l1x, st + 2);
  wave_reduce_atomic(l1y, st + 3);
  wave_reduce_atomic(l1z, st + 4);
  wave_reduce_atomic(lxx, st + 5);
  wave_reduce_atomic(lyy, st + 6);
  wave_reduce_atomic(lzz, st + 7);
  wave_reduce_atomic(lxy, st + 8);
  wave_reduce_atomic(lxz, st + 9);
  wave_reduce_atomic(lyz, st + 10);
}

// ---------------- Kernel 3: fold BN into affine params ------------------------
__global__ void finalize_params(const double* __restrict__ st,
                                const float* __restrict__ wn_w,
                                const float* __restrict__ wn_g,
                                const float* __restrict__ wn_be,
                                const float* __restrict__ dn_w1,
                                const float* __restrict__ dn_g1,
                                const float* __restrict__ dn_be1,
                                float* __restrict__ prm) {
  const double M = (double)NROWS * 16.0;  // 262144
  int t = threadIdx.x;
  if (t < 32) {
    double m0 = st[2] / M, m1 = st[3] / M, m2 = st[4] / M;
    double cxx = st[5] / M - m0 * m0, cyy = st[6] / M - m1 * m1, czz = st[7] / M - m2 * m2;
    double cxy = st[8] / M - m0 * m1, cxz = st[9] / M - m0 * m2, cyz = st[10] / M - m1 * m2;
    double w0 = wn_w[t * 3], w1 = wn_w[t * 3 + 1], w2 = wn_w[t * 3 + 2];
    double var = w0 * w0 * cxx + w1 * w1 * cyy + w2 * w2 * czz
               + 2.0 * (w0 * w1 * cxy + w0 * w2 * cxz + w1 * w2 * cyz);
    double alpha = (double)wn_g[t] / sqrt(var + 1e-5);
    double a0 = alpha * w0, a1 = alpha * w1, a2 = alpha * w2;
    prm[t * 3] = (float)a0; prm[t * 3 + 1] = (float)a1; prm[t * 3 + 2] = (float)a2;
    prm[96 + t] = (float)((double)wn_be[t] - (a0 * m0 + a1 * m1 + a2 * m2));
  } else if (t < 48) {
    int ch = t - 32;
    double mx = st[0] / M;
    double vx = st[1] / M - mx * mx;
    double w = dn_w1[ch];
    double alpha = (double)dn_g1[ch] * w / sqrt(w * w * vx + 1e-5);
    prm[128 + ch] = (float)alpha;
    prm[144 + ch] = (float)((double)dn_be1[ch] - alpha * mx);
  }
}

// ---------------- Kernel 4: transpose Linear weight ---------------------------
__global__ __launch_bounds__(256) void transpose_L(const float* __restrict__ lin_w,
                                                   float* __restrict__ LT) {
  int g = blockIdx.x * 256 + threadIdx.x;  // g = cw*64 + o
  int o = g & 63, cw = g >> 6;
  LT[g] = lin_w[o * 2048 + cw];
}

// ---------------- Kernel 5: density scale (sigmoid MLP) -----------------------
__global__ __launch_bounds__(256) void ds_kernel(const float* __restrict__ xbuf,
                                                 const float* __restrict__ prm,
                                                 const float* __restrict__ dn_w2,
                                                 const float* __restrict__ dn_b2,
                                                 float* __restrict__ dsbuf) {
  int r = blockIdx.x * 256 + threadIdx.x;
  float A[16], Bp[16], W2[16];
#pragma unroll
  for (int ch = 0; ch < 16; ++ch) {
    A[ch] = prm[128 + ch];
    Bp[ch] = prm[144 + ch];
    W2[ch] = dn_w2[ch];
  }
  float b2 = dn_b2[0];
#pragma unroll
  for (int k = 0; k < 16; ++k) {
    float x = xbuf[(size_t)r * 16 + k];
    float s = b2;
#pragma unroll
    for (int ch = 0; ch < 16; ++ch) s = fmaf(W2[ch], fmaxf(fmaf(A[ch], x, Bp[ch]), 0.f), s);
    dsbuf[(size_t)r * 16 + k] = 1.f / (1.f + expf(-s));
  }
}

// ---------------- Kernel 6: per-point matmul + Linear -------------------------
// block = 256 threads, 16 points. Phases per c-chunk (8 channels):
//  stage xd (gather*ds) -> phase A feat = xd . wt -> phase B acc += LT^T feat
__global__ __launch_bounds__(256, 2) void pc_main(const float* __restrict__ inputs,
                                                  const float* __restrict__ pos,
                                                  const int* __restrict__ nn_idx,
                                                  const float* __restrict__ dsbuf,
                                                  const float* __restrict__ prm_g,
                                                  const float* __restrict__ LT,
                                                  const float* __restrict__ lin_b,
                                                  float* __restrict__ out) {
  __shared__ float smem[WT_PSTR * 16 + 2048 + 5120];
  __shared__ int idx_s[256];
  __shared__ float dsh[256];
  __shared__ float prm[160];
  float* wt_s = smem;                    // [p]*648 + [w]*20 + k
  float* xd_s = smem + WT_PSTR * 16;     // (c*16+p)*16 + k
  float* feat_s = xd_s + 2048;           // cw*20 + p
  float* red = xd_s;                     // alias (4096 floats) for final reduce

  int t = threadIdx.x;
  int p0 = blockIdx.x << 4;
  int b = p0 >> 12;
  int n0 = p0 & (NPTS - 1);
  const float* pb = pos + b * 3 * NPTS;
  const float* inb = inputs + (size_t)b * NC * NPTS;

  if (t < 160) prm[t] = prm_g[t];
  int pp = t >> 4, kk = t & 15;
  {
    int r = p0 + pp;
    idx_s[t] = nn_idx[(size_t)r * 16 + kk];
    dsh[t] = dsbuf[(size_t)r * 16 + kk];
  }
  __syncthreads();
  {
    int n = n0 + pp;
    int j = idx_s[t];
    float lx = pb[j] - pb[n];
    float ly = pb[NPTS + j] - pb[NPTS + n];
    float lz = pb[2 * NPTS + j] - pb[2 * NPTS + n];
    float* wrow = wt_s + pp * WT_PSTR + kk;
#pragma unroll
    for (int w = 0; w < 32; ++w) {
      float v = prm[96 + w];
      v = fmaf(prm[w * 3], lx, v);
      v = fmaf(prm[w * 3 + 1], ly, v);
      v = fmaf(prm[w * 3 + 2], lz, v);
      wrow[w * 20] = fmaxf(v, 0.f);
    }
  }

  float acc0[16], acc1[16];
#pragma unroll
  for (int i = 0; i < 16; ++i) { acc0[i] = 0.f; acc1[i] = 0.f; }
  int oh = t & 31;
  int sl = t >> 5;   // 8 slices (also phase-A c-tile)
  int wA = t & 31;

  for (int cc = 0; cc < 8; ++cc) {
    // ---- stage xd (safe: previous phase A finished at its barrier) ----
#pragma unroll
    for (int i = 0; i < 8; ++i) {
      int L = i * 256 + t;
      int k = L & 15, p = (L >> 4) & 15, c = L >> 8;
      int j = idx_s[p * 16 + k];
      xd_s[(c * 16 + p) * 16 + k] = inb[(size_t)(cc * 8 + c) * NPTS + j] * dsh[p * 16 + k];
    }
    __syncthreads();
    // ---- phase A: feat[cw][p] = sum_k xd[c][p][k]*wt[p][w][k] ----
    {
      int ct = sl;
#pragma unroll 2
      for (int p = 0; p < 16; ++p) {
        const float4* xq = (const float4*)(xd_s + (ct * 16 + p) * 16);
        const float4* wq = (const float4*)(wt_s + p * WT_PSTR + wA * 20);
        float xv[16], wv[16];
        *(float4*)&xv[0] = xq[0]; *(float4*)&xv[4] = xq[1];
        *(float4*)&xv[8] = xq[2]; *(float4*)&xv[12] = xq[3];
        *(float4*)&wv[0] = wq[0]; *(float4*)&wv[4] = wq[1];
        *(float4*)&wv[8] = wq[2]; *(float4*)&wv[12] = wq[3];
        float f = 0.f;
#pragma unroll
        for (int i = 0; i < 16; ++i) f = fmaf(xv[i], wv[i], f);
        feat_s[(ct * 32 + wA) * 20 + p] = f;
      }
    }
    __syncthreads();
    // ---- phase B: acc[o][p] += LT[cw][o] * feat[cw][p] ----
    {
      const float* Lrow = LT + (size_t)(cc * 256) * 64;
#pragma unroll 4
      for (int m = 0; m < 32; ++m) {
        int cwl = sl * 32 + m;
        float Lv0 = Lrow[cwl * 64 + oh];
        float Lv1 = Lrow[cwl * 64 + 32 + oh];
        const float4* fq = (const float4*)(feat_s + cwl * 20);
        float fv[16];
        *(float4*)&fv[0] = fq[0]; *(float4*)&fv[4] = fq[1];
        *(float4*)&fv[8] = fq[2]; *(float4*)&fv[12] = fq[3];
#pragma unroll
        for (int i = 0; i < 16; ++i) {
          acc0[i] = fmaf(Lv0, fv[i], acc0[i]);
          acc1[i] = fmaf(Lv1, fv[i], acc1[i]);
        }
      }
    }
    // no barrier needed: next stage writes xd only; phase A of cc+1 is
    // separated from this phase B by the post-stage barrier.
  }
  __syncthreads();  // protect alias region (feat reads done everywhere)

  // staged slice reduction 8 -> 4 -> 2 -> 1
  if (sl >= 4) {
    float* q = red + ((sl - 4) * 32 + oh) * 32;
#pragma unroll
    for (int i = 0; i < 16; ++i) { q[i] = acc0[i]; q[16 + i] = acc1[i]; }
  }
  __syncthreads();
  if (sl < 4) {
    const float* q = red + (sl * 32 + oh) * 32;
#pragma unroll
    for (int i = 0; i < 16; ++i) { acc0[i] += q[i]; acc1[i] += q[16 + i]; }
  }
  __syncthreads();
  if (sl == 2 || sl == 3) {
    float* q = red + ((sl - 2) * 32 + oh) * 32;
#pragma unroll
    for (int i = 0; i < 16; ++i) { q[i] = acc0[i]; q[16 + i] = acc1[i]; }
  }
  __syncthreads();
  if (sl < 2) {
    const float* q = red + (sl * 32 + oh) * 32;
#pragma unroll
    for (int i = 0; i < 16; ++i) { acc0[i] += q[i]; acc1[i] += q[16 + i]; }
  }
  __syncthreads();
  if (sl == 1) {
    float* q = red + oh * 32;
#pragma unroll
    for (int i = 0; i < 16; ++i) { q[i] = acc0[i]; q[16 + i] = acc1[i]; }
  }
  __syncthreads();
  if (sl == 0) {
    const float* q = red + oh * 32;
#pragma unroll
    for (int i = 0; i < 16; ++i) { acc0[i] += q[i]; acc1[i] += q[16 + i]; }
    float b0 = lin_b[oh], b1 = lin_b[oh + 32];
    float4* o0 = (float4*)(out + (size_t)(b * 64 + oh) * NPTS + n0);
    float4* o1 = (float4*)(out + (size_t)(b * 64 + oh + 32) * NPTS + n0);
#pragma unroll
    for (int qd = 0; qd < 4; ++qd) {
      float4 v0, v1;
      v0.x = acc0[qd * 4] + b0;  v0.y = acc0[qd * 4 + 1] + b0;
      v0.z = acc0[qd * 4 + 2] + b0; v0.w = acc0[qd * 4 + 3] + b0;
      v1.x = acc1[qd * 4] + b1;  v1.y = acc1[qd * 4 + 1] + b1;
      v1.z = acc1[qd * 4 + 2] + b1; v1.w = acc1[qd * 4 + 3] + b1;
      o0[qd] = v0; o1[qd] = v1;
    }
  }
}

// ------------------------------- launch ---------------------------------------
extern "C" void kernel_launch(void* const* d_in, const int* in_sizes, int n_in,
                              void* d_out, int out_size, void* d_ws, size_t ws_size,
                              hipStream_t stream) {
  (void)in_sizes; (void)n_in; (void)out_size; (void)ws_size;
  const float* inputs = (const float*)d_in[0];
  const float* pos    = (const float*)d_in[1];
  const float* invd   = (const float*)d_in[2];
  const float* wn_w   = (const float*)d_in[3];
  const float* wn_g   = (const float*)d_in[5];
  const float* wn_be  = (const float*)d_in[6];
  const float* dn_w1  = (const float*)d_in[7];
  const float* dn_g1  = (const float*)d_in[9];
  const float* dn_be1 = (const float*)d_in[10];
  const float* dn_w2  = (const float*)d_in[11];
  const float* dn_b2  = (const float*)d_in[12];
  const float* lin_w  = (const float*)d_in[13];
  const float* lin_b  = (const float*)d_in[14];
  float* outp = (float*)d_out;

  char* ws = (char*)d_ws;
  double* stats = (double*)ws;                    // 11 doubles
  float* prm    = (float*)(ws + 128);             // 160 floats
  float* LT     = (float*)(ws + 1024);            // 512 KB
  int*   nnidx  = (int*)(ws + (1u << 20));        // 1 MB
  float* xbuf   = (float*)(ws + (2u << 20));      // 1 MB
  float* dsbuf  = (float*)(ws + (3u << 20));      // 1 MB
  int*   pi     = (int*)(ws + (4u << 20));        // 8 MB

  hipMemsetAsync(stats, 0, 128, stream);
  knn_partial<<<dim3(64, NCHUNK), 256, 0, stream>>>(pos, pi);
  merge_stats<<<64, 256, 0, stream>>>(pos, invd, pi, nnidx, xbuf, stats);
  finalize_params<<<1, 64, 0, stream>>>(stats, wn_w, wn_g, wn_be, dn_w1, dn_g1, dn_be1, prm);
  transpose_L<<<512, 256, 0, stream>>>(lin_w, LT);
  ds_kernel<<<64, 256, 0, stream>>>(xbuf, prm, dn_w2, dn_b2, dsbuf);
  pc_main<<<1024, 256, 0, stream>>>(inputs, pos, nnidx, dsbuf, prm, LT, lin_b, outp);
}

// Round 2
// 282.031 us; speedup vs baseline: 1.9333x; 1.9333x over previous
//
#include <hip/hip_runtime.h>
#include <math.h>

// Problem constants
#define NB 4
#define NC 64
#define NPTS 4096
#define NK 16
#define NROWS (NB*NPTS)      // 16384
#define NCHUNK 16            // KNN candidate chunks
#define CHSZ (NPTS/NCHUNK)   // 256
#define WT_PSTR 648          // LDS stride per point for wt tile [16][32][20]+pad

// ---------------- top-16 insertion (sorted ascending, dd[15]=max) -------------
__device__ __forceinline__ void insert16(double dist, int j, double (&dd)[16], int (&ii)[16]) {
  double cd = dist; int ci = j;
#pragma unroll
  for (int s = 0; s < 16; ++s) {
    double od = dd[s]; int oi = ii[s];
    bool c = cd < od;
    dd[s] = c ? cd : od;
    ii[s] = c ? ci : oi;
    cd = c ? od : cd;
    ci = c ? oi : ci;
  }
}

__device__ __forceinline__ void wave_reduce_atomic(double v, double* dst) {
#pragma unroll
  for (int off = 32; off; off >>= 1) v += __shfl_down(v, off, 64);
  if ((threadIdx.x & 63) == 0) atomicAdd(dst, v);
}

// ---------------- Kernel 0: pack positions as float4 --------------------------
__global__ __launch_bounds__(256) void pack_pos4(const float* __restrict__ pos,
                                                 float4* __restrict__ pos4) {
  int g = blockIdx.x * 256 + threadIdx.x;   // 4*4096 total
  int b = g >> 12, n = g & (NPTS - 1);
  const float* pb = pos + b * 3 * NPTS;
  pos4[g] = make_float4(pb[n], pb[NPTS + n], pb[2 * NPTS + n], 0.f);
}

// ---------------- Kernel 1: partial KNN over candidate chunk ------------------
// Packed u32 keys: (f32 dist bits & ~0xFFF) | candidate index. Unconditional
// min/max bubble insert: 2 VALU/step, no branch, no vcc chain.
__global__ __launch_bounds__(256) void knn_partial(const float4* __restrict__ pos4,
                                                   uint4* __restrict__ keys) {
  __shared__ float4 cand[CHSZ];
  int t = threadIdx.x;
  int row0 = blockIdx.x * 256;
  int b = row0 >> 12;
  int j0 = blockIdx.y * CHSZ;
  const float4* pb = pos4 + b * NPTS;
  cand[t] = pb[j0 + t];
  __syncthreads();
  float4 q = pb[(row0 + t) & (NPTS - 1)];
  unsigned dd[16];
#pragma unroll
  for (int s = 0; s < 16; ++s) dd[s] = 0xFFFFFFFFu;
#pragma unroll 4
  for (int jj = 0; jj < CHSZ; ++jj) {
    float4 c = cand[jj];
    float dx = q.x - c.x, dy = q.y - c.y, dz = q.z - c.z;
    float d = fmaf(dx, dx, fmaf(dy, dy, dz * dz));
    unsigned key = (__float_as_uint(d) & 0xFFFFF000u) | (unsigned)(j0 + jj);
#pragma unroll
    for (int s = 0; s < 16; ++s) {
      unsigned lo = min(key, dd[s]);
      key = max(key, dd[s]);
      dd[s] = lo;
    }
  }
  uint4* po = keys + ((size_t)blockIdx.y * NROWS + row0 + t) * 4;
  po[0] = make_uint4(dd[0], dd[1], dd[2], dd[3]);
  po[1] = make_uint4(dd[4], dd[5], dd[6], dd[7]);
  po[2] = make_uint4(dd[8], dd[9], dd[10], dd[11]);
  po[3] = make_uint4(dd[12], dd[13], dd[14], dd[15]);
}

// ------- Kernel 2: merge packed partials, exact f64 re-rank, BN stats ---------
__global__ __launch_bounds__(256) void merge_stats(const float4* __restrict__ pos4,
                                                   const float* __restrict__ invd,
                                                   const uint4* __restrict__ keys,
                                                   int* __restrict__ nn_idx,
                                                   float* __restrict__ xbuf,
                                                   double* __restrict__ st) {
  int r = blockIdx.x * blockDim.x + threadIdx.x;
  int b = r >> 12, n = r & (NPTS - 1);

  // merge 16 sorted chunk lists into packed top-24 (margin for truncation)
  unsigned top[24];
#pragma unroll
  for (int s = 0; s < 24; ++s) top[s] = 0xFFFFFFFFu;
  for (int c = 0; c < NCHUNK; ++c) {
    const uint4* ps = keys + ((size_t)c * NROWS + r) * 4;
    unsigned kk[16];
    uint4 u0 = ps[0], u1 = ps[1], u2 = ps[2], u3 = ps[3];
    kk[0]=u0.x; kk[1]=u0.y; kk[2]=u0.z; kk[3]=u0.w;
    kk[4]=u1.x; kk[5]=u1.y; kk[6]=u1.z; kk[7]=u1.w;
    kk[8]=u2.x; kk[9]=u2.y; kk[10]=u2.z; kk[11]=u2.w;
    kk[12]=u3.x; kk[13]=u3.y; kk[14]=u3.z; kk[15]=u3.w;
#pragma unroll 4
    for (int s = 0; s < 16; ++s) {
      unsigned key = kk[s];
      if (key >= top[23]) break;          // chunk list sorted ascending
#pragma unroll
      for (int q2 = 0; q2 < 24; ++q2) {
        unsigned lo = min(key, top[q2]);
        key = max(key, top[q2]);
        top[q2] = lo;
      }
    }
  }

  // exact f64 re-rank of the 24 survivors — final set matches numpy-f64
  const float4* pb = pos4 + b * NPTS;
  float4 qp = pb[n];
  double xi = qp.x, yi = qp.y, zi = qp.z;
  double dd[16]; int ii[16];
#pragma unroll
  for (int s = 0; s < 16; ++s) { dd[s] = 1e300; ii[s] = 0; }
#pragma unroll 4
  for (int s = 0; s < 24; ++s) {
    int j = (int)(top[s] & 0xFFFu);
    float4 cj = pb[j];
    double dx = xi - (double)cj.x;
    double dy = yi - (double)cj.y;
    double dz = zi - (double)cj.z;
    double dist = dx * dx + dy * dy + dz * dz;
    if (dist < dd[15]) insert16(dist, j, dd, ii);
  }

  // write final indices; gather inverse density
  const float* ivb = invd + b * NPTS;
  float xv[16];
  float vmax = -1e30f;
#pragma unroll
  for (int s = 0; s < 16; ++s) {
    int j = ii[s];
    nn_idx[(size_t)r * 16 + s] = j;
    float v = ivb[j];
    xv[s] = v;
    vmax = fmaxf(vmax, v);
  }
  double sx = 0, sxx = 0;
  double l1x = 0, l1y = 0, l1z = 0;
  double lxx = 0, lyy = 0, lzz = 0, lxy = 0, lxz = 0, lyz = 0;
#pragma unroll
  for (int s = 0; s < 16; ++s) {
    float x = xv[s] / vmax;
    xbuf[(size_t)r * 16 + s] = x;
    sx += x; sxx += (double)x * (double)x;
    int j = ii[s];
    float4 cj = pb[j];
    double lx = (double)cj.x - xi;
    double ly = (double)cj.y - yi;
    double lz = (double)cj.z - zi;
    l1x += lx; l1y += ly; l1z += lz;
    lxx += lx * lx; lyy += ly * ly; lzz += lz * lz;
    lxy += lx * ly; lxz += lx * lz; lyz += ly * lz;
  }
  wave_reduce_atomic(sx, st + 0);
  wave_reduce_atomic(sxx, st + 1);
  wave_reduce_atomic(l1x, st + 2);
  wave_reduce_atomic(l1y, st + 3);
  wave_reduce_atomic(l1z, st + 4);
  wave_reduce_atomic(lxx, st + 5);
  wave_reduce_atomic(lyy, st + 6);
  wave_reduce_atomic(lzz, st + 7);
  wave_reduce_atomic(lxy, st + 8);
  wave_reduce_atomic(lxz, st + 9);
  wave_reduce_atomic(lyz, st + 10);
}

// ---------------- Kernel 3: fold BN into affine params ------------------------
__global__ void finalize_params(const double* __restrict__ st,
                                const float* __restrict__ wn_w,
                                const float* __restrict__ wn_g,
                                const float* __restrict__ wn_be,
                                const float* __restrict__ dn_w1,
                                const float* __restrict__ dn_g1,
                                const float* __restrict__ dn_be1,
                                float* __restrict__ prm) {
  const double M = (double)NROWS * 16.0;  // 262144
  int t = threadIdx.x;
  if (t < 32) {
    double m0 = st[2] / M, m1 = st[3] / M, m2 = st[4] / M;
    double cxx = st[5] / M - m0 * m0, cyy = st[6] / M - m1 * m1, czz = st[7] / M - m2 * m2;
    double cxy = st[8] / M - m0 * m1, cxz = st[9] / M - m0 * m2, cyz = st[10] / M - m1 * m2;
    double w0 = wn_w[t * 3], w1 = wn_w[t * 3 + 1], w2 = wn_w[t * 3 + 2];
    double var = w0 * w0 * cxx + w1 * w1 * cyy + w2 * w2 * czz
               + 2.0 * (w0 * w1 * cxy + w0 * w2 * cxz + w1 * w2 * cyz);
    double alpha = (double)wn_g[t] / sqrt(var + 1e-5);
    double a0 = alpha * w0, a1 = alpha * w1, a2 = alpha * w2;
    prm[t * 3] = (float)a0; prm[t * 3 + 1] = (float)a1; prm[t * 3 + 2] = (float)a2;
    prm[96 + t] = (float)((double)wn_be[t] - (a0 * m0 + a1 * m1 + a2 * m2));
  } else if (t < 48) {
    int ch = t - 32;
    double mx = st[0] / M;
    double vx = st[1] / M - mx * mx;
    double w = dn_w1[ch];
    double alpha = (double)dn_g1[ch] * w / sqrt(w * w * vx + 1e-5);
    prm[128 + ch] = (float)alpha;
    prm[144 + ch] = (float)((double)dn_be1[ch] - alpha * mx);
  }
}

// ---------------- Kernel 4: transpose Linear weight ---------------------------
__global__ __launch_bounds__(256) void transpose_L(const float* __restrict__ lin_w,
                                                   float* __restrict__ LT) {
  int g = blockIdx.x * 256 + threadIdx.x;  // g = cw*64 + o
  int o = g & 63, cw = g >> 6;
  LT[g] = lin_w[o * 2048 + cw];
}

// ---------------- Kernel 5: density scale (sigmoid MLP) -----------------------
__global__ __launch_bounds__(256) void ds_kernel(const float* __restrict__ xbuf,
                                                 const float* __restrict__ prm,
                                                 const float* __restrict__ dn_w2,
                                                 const float* __restrict__ dn_b2,
                                                 float* __restrict__ dsbuf) {
  int r = blockIdx.x * 256 + threadIdx.x;
  float A[16], Bp[16], W2[16];
#pragma unroll
  for (int ch = 0; ch < 16; ++ch) {
    A[ch] = prm[128 + ch];
    Bp[ch] = prm[144 + ch];
    W2[ch] = dn_w2[ch];
  }
  float b2 = dn_b2[0];
#pragma unroll
  for (int k = 0; k < 16; ++k) {
    float x = xbuf[(size_t)r * 16 + k];
    float s = b2;
#pragma unroll
    for (int ch = 0; ch < 16; ++ch) s = fmaf(W2[ch], fmaxf(fmaf(A[ch], x, Bp[ch]), 0.f), s);
    dsbuf[(size_t)r * 16 + k] = 1.f / (1.f + expf(-s));
  }
}

// ---------------- Kernel 6: per-point matmul + Linear -------------------------
// block = 256 threads, 16 points. Phases per c-chunk (8 channels):
//  stage xd (gather*ds) -> phase A feat = xd . wt -> phase B acc += LT^T feat
__global__ __launch_bounds__(256, 2) void pc_main(const float* __restrict__ inputs,
                                                  const float* __restrict__ pos,
                                                  const int* __restrict__ nn_idx,
                                                  const float* __restrict__ dsbuf,
                                                  const float* __restrict__ prm_g,
                                                  const float* __restrict__ LT,
                                                  const float* __restrict__ lin_b,
                                                  float* __restrict__ out) {
  __shared__ float smem[WT_PSTR * 16 + 2048 + 5120];
  __shared__ int idx_s[256];
  __shared__ float dsh[256];
  __shared__ float prm[160];
  float* wt_s = smem;                    // [p]*648 + [w]*20 + k
  float* xd_s = smem + WT_PSTR * 16;     // (c*16+p)*16 + k
  float* feat_s = xd_s + 2048;           // cw*20 + p
  float* red = xd_s;                     // alias (4096 floats) for final reduce

  int t = threadIdx.x;
  int p0 = blockIdx.x << 4;
  int b = p0 >> 12;
  int n0 = p0 & (NPTS - 1);
  const float* pb = pos + b * 3 * NPTS;
  const float* inb = inputs + (size_t)b * NC * NPTS;

  if (t < 160) prm[t] = prm_g[t];
  int pp = t >> 4, kk = t & 15;
  {
    int r = p0 + pp;
    idx_s[t] = nn_idx[(size_t)r * 16 + kk];
    dsh[t] = dsbuf[(size_t)r * 16 + kk];
  }
  __syncthreads();
  {
    int n = n0 + pp;
    int j = idx_s[t];
    float lx = pb[j] - pb[n];
    float ly = pb[NPTS + j] - pb[NPTS + n];
    float lz = pb[2 * NPTS + j] - pb[2 * NPTS + n];
    float* wrow = wt_s + pp * WT_PSTR + kk;
#pragma unroll
    for (int w = 0; w < 32; ++w) {
      float v = prm[96 + w];
      v = fmaf(prm[w * 3], lx, v);
      v = fmaf(prm[w * 3 + 1], ly, v);
      v = fmaf(prm[w * 3 + 2], lz, v);
      wrow[w * 20] = fmaxf(v, 0.f);
    }
  }

  float acc0[16], acc1[16];
#pragma unroll
  for (int i = 0; i < 16; ++i) { acc0[i] = 0.f; acc1[i] = 0.f; }
  int oh = t & 31;
  int sl = t >> 5;   // 8 slices (also phase-A c-tile)
  int wA = t & 31;

  for (int cc = 0; cc < 8; ++cc) {
    // ---- stage xd (safe: previous phase A finished at its barrier) ----
#pragma unroll
    for (int i = 0; i < 8; ++i) {
      int L = i * 256 + t;
      int k = L & 15, p = (L >> 4) & 15, c = L >> 8;
      int j = idx_s[p * 16 + k];
      xd_s[(c * 16 + p) * 16 + k] = inb[(size_t)(cc * 8 + c) * NPTS + j] * dsh[p * 16 + k];
    }
    __syncthreads();
    // ---- phase A: feat[cw][p] = sum_k xd[c][p][k]*wt[p][w][k] ----
    {
      int ct = sl;
#pragma unroll 2
      for (int p = 0; p < 16; ++p) {
        const float4* xq = (const float4*)(xd_s + (ct * 16 + p) * 16);
        const float4* wq = (const float4*)(wt_s + p * WT_PSTR + wA * 20);
        float xv[16], wv[16];
        *(float4*)&xv[0] = xq[0]; *(float4*)&xv[4] = xq[1];
        *(float4*)&xv[8] = xq[2]; *(float4*)&xv[12] = xq[3];
        *(float4*)&wv[0] = wq[0]; *(float4*)&wv[4] = wq[1];
        *(float4*)&wv[8] = wq[2]; *(float4*)&wv[12] = wq[3];
        float f = 0.f;
#pragma unroll
        for (int i = 0; i < 16; ++i) f = fmaf(xv[i], wv[i], f);
        feat_s[(ct * 32 + wA) * 20 + p] = f;
      }
    }
    __syncthreads();
    // ---- phase B: acc[o][p] += LT[cw][o] * feat[cw][p] ----
    {
      const float* Lrow = LT + (size_t)(cc * 256) * 64;
#pragma unroll 4
      for (int m = 0; m < 32; ++m) {
        int cwl = sl * 32 + m;
        float Lv0 = Lrow[cwl * 64 + oh];
        float Lv1 = Lrow[cwl * 64 + 32 + oh];
        const float4* fq = (const float4*)(feat_s + cwl * 20);
        float fv[16];
        *(float4*)&fv[0] = fq[0]; *(float4*)&fv[4] = fq[1];
        *(float4*)&fv[8] = fq[2]; *(float4*)&fv[12] = fq[3];
#pragma unroll
        for (int i = 0; i < 16; ++i) {
          acc0[i] = fmaf(Lv0, fv[i], acc0[i]);
          acc1[i] = fmaf(Lv1, fv[i], acc1[i]);
        }
      }
    }
    // no barrier needed: next stage writes xd only; phase A of cc+1 is
    // separated from this phase B by the post-stage barrier.
  }
  __syncthreads();  // protect alias region (feat reads done everywhere)

  // staged slice reduction 8 -> 4 -> 2 -> 1
  if (sl >= 4) {
    float* q = red + ((sl - 4) * 32 + oh) * 32;
#pragma unroll
    for (int i = 0; i < 16; ++i) { q[i] = acc0[i]; q[16 + i] = acc1[i]; }
  }
  __syncthreads();
  if (sl < 4) {
    const float* q = red + (sl * 32 + oh) * 32;
#pragma unroll
    for (int i = 0; i < 16; ++i) { acc0[i] += q[i]; acc1[i] += q[16 + i]; }
  }
  __syncthreads();
  if (sl == 2 || sl == 3) {
    float* q = red + ((sl - 2) * 32 + oh) * 32;
#pragma unroll
    for (int i = 0; i < 16; ++i) { q[i] = acc0[i]; q[16 + i] = acc1[i]; }
  }
  __syncthreads();
  if (sl < 2) {
    const float* q = red + (sl * 32 + oh) * 32;
#pragma unroll
    for (int i = 0; i < 16; ++i) { acc0[i] += q[i]; acc1[i] += q[16 + i]; }
  }
  __syncthreads();
  if (sl == 1) {
    float* q = red + oh * 32;
#pragma unroll
    for (int i = 0; i < 16; ++i) { q[i] = acc0[i]; q[16 + i] = acc1[i]; }
  }
  __syncthreads();
  if (sl == 0) {
    const float* q = red + oh * 32;
#pragma unroll
    for (int i = 0; i < 16; ++i) { acc0[i] += q[i]; acc1[i] += q[16 + i]; }
    float b0 = lin_b[oh], b1 = lin_b[oh + 32];
    float4* o0 = (float4*)(out + (size_t)(b * 64 + oh) * NPTS + n0);
    float4* o1 = (float4*)(out + (size_t)(b * 64 + oh + 32) * NPTS + n0);
#pragma unroll
    for (int qd = 0; qd < 4; ++qd) {
      float4 v0, v1;
      v0.x = acc0[qd * 4] + b0;  v0.y = acc0[qd * 4 + 1] + b0;
      v0.z = acc0[qd * 4 + 2] + b0; v0.w = acc0[qd * 4 + 3] + b0;
      v1.x = acc1[qd * 4] + b1;  v1.y = acc1[qd * 4 + 1] + b1;
      v1.z = acc1[qd * 4 + 2] + b1; v1.w = acc1[qd * 4 + 3] + b1;
      o0[qd] = v0; o1[qd] = v1;
    }
  }
}

// ------------------------------- launch ---------------------------------------
extern "C" void kernel_launch(void* const* d_in, const int* in_sizes, int n_in,
                              void* d_out, int out_size, void* d_ws, size_t ws_size,
                              hipStream_t stream) {
  (void)in_sizes; (void)n_in; (void)out_size; (void)ws_size;
  const float* inputs = (const float*)d_in[0];
  const float* pos    = (const float*)d_in[1];
  const float* invd   = (const float*)d_in[2];
  const float* wn_w   = (const float*)d_in[3];
  const float* wn_g   = (const float*)d_in[5];
  const float* wn_be  = (const float*)d_in[6];
  const float* dn_w1  = (const float*)d_in[7];
  const float* dn_g1  = (const float*)d_in[9];
  const float* dn_be1 = (const float*)d_in[10];
  const float* dn_w2  = (const float*)d_in[11];
  const float* dn_b2  = (const float*)d_in[12];
  const float* lin_w  = (const float*)d_in[13];
  const float* lin_b  = (const float*)d_in[14];
  float* outp = (float*)d_out;

  char* ws = (char*)d_ws;
  double* stats = (double*)ws;                    // 11 doubles
  float*  prm   = (float*)(ws + 128);             // 160 floats
  float*  LT    = (float*)(ws + 1024);            // 512 KB
  int*    nnidx = (int*)(ws + (1u << 20));        // 1 MB
  float*  xbuf  = (float*)(ws + (2u << 20));      // 1 MB
  float*  dsbuf = (float*)(ws + (3u << 20));      // 1 MB
  float4* pos4  = (float4*)(ws + (4u << 20));     // 256 KB
  uint4*  keys  = (uint4*)(ws + (5u << 20));      // 16 MB

  hipMemsetAsync(stats, 0, 128, stream);
  pack_pos4<<<64, 256, 0, stream>>>(pos, pos4);
  knn_partial<<<dim3(64, NCHUNK), 256, 0, stream>>>(pos4, keys);
  merge_stats<<<64, 256, 0, stream>>>(pos4, invd, keys, nnidx, xbuf, stats);
  finalize_params<<<1, 64, 0, stream>>>(stats, wn_w, wn_g, wn_be, dn_w1, dn_g1, dn_be1, prm);
  transpose_L<<<512, 256, 0, stream>>>(lin_w, LT);
  ds_kernel<<<64, 256, 0, stream>>>(xbuf, prm, dn_w2, dn_b2, dsbuf);
  pc_main<<<1024, 256, 0, stream>>>(inputs, pos, nnidx, dsbuf, prm, LT, lin_b, outp);
}

// Round 4
// 257.615 us; speedup vs baseline: 2.1165x; 1.0948x over previous
//
#include <hip/hip_runtime.h>
#include <math.h>

// Problem constants
#define NB 4
#define NC 64
#define NPTS 4096
#define NROWS (NB*NPTS)      // 16384
#define NCHUNK 16            // KNN candidate chunks
#define CHSZ (NPTS/NCHUNK)   // 256

typedef __attribute__((ext_vector_type(4))) float f32x4;
typedef __bf16 bf16x8 __attribute__((ext_vector_type(8)));

__device__ __forceinline__ ushort f2bf(float f) {
  unsigned u = __float_as_uint(f);
  u = (u + 0x7FFFu + ((u >> 16) & 1u)) >> 16;   // RNE
  return (ushort)u;
}
__device__ __forceinline__ unsigned pk2(float lo, float hi) {
  return (unsigned)f2bf(lo) | ((unsigned)f2bf(hi) << 16);
}

// ---------------- top-16 insertion (sorted ascending, dd[15]=max) -------------
__device__ __forceinline__ void insert16(double dist, int j, double (&dd)[16], int (&ii)[16]) {
  double cd = dist; int ci = j;
#pragma unroll
  for (int s = 0; s < 16; ++s) {
    double od = dd[s]; int oi = ii[s];
    bool c = cd < od;
    dd[s] = c ? cd : od;
    ii[s] = c ? ci : oi;
    cd = c ? od : cd;
    ci = c ? oi : ci;
  }
}

__device__ __forceinline__ void wave_reduce_atomic(double v, double* dst) {
#pragma unroll
  for (int off = 32; off; off >>= 1) v += __shfl_down(v, off, 64);
  if ((threadIdx.x & 63) == 0) atomicAdd(dst, v);
}

// ---------------- Kernel 0: pack positions as float4 --------------------------
__global__ __launch_bounds__(256) void pack_pos4(const float* __restrict__ pos,
                                                 float4* __restrict__ pos4) {
  int g = blockIdx.x * 256 + threadIdx.x;   // 4*4096 total
  int b = g >> 12, n = g & (NPTS - 1);
  const float* pb = pos + b * 3 * NPTS;
  pos4[g] = make_float4(pb[n], pb[NPTS + n], pb[2 * NPTS + n], 0.f);
}

// ---------------- Kernel 1: partial KNN over candidate chunk ------------------
__global__ __launch_bounds__(256) void knn_partial(const float4* __restrict__ pos4,
                                                   uint4* __restrict__ keys) {
  __shared__ float4 cand[CHSZ];
  int t = threadIdx.x;
  int row0 = blockIdx.x * 256;
  int b = row0 >> 12;
  int j0 = blockIdx.y * CHSZ;
  const float4* pb = pos4 + b * NPTS;
  cand[t] = pb[j0 + t];
  __syncthreads();
  float4 q = pb[(row0 + t) & (NPTS - 1)];
  unsigned dd[16];
#pragma unroll
  for (int s = 0; s < 16; ++s) dd[s] = 0xFFFFFFFFu;
#pragma unroll 4
  for (int jj = 0; jj < CHSZ; ++jj) {
    float4 c = cand[jj];
    float dx = q.x - c.x, dy = q.y - c.y, dz = q.z - c.z;
    float d = fmaf(dx, dx, fmaf(dy, dy, dz * dz));
    unsigned key = (__float_as_uint(d) & 0xFFFFF000u) | (unsigned)(j0 + jj);
#pragma unroll
    for (int s = 0; s < 16; ++s) {
      unsigned lo = min(key, dd[s]);
      key = max(key, dd[s]);
      dd[s] = lo;
    }
  }
  uint4* po = keys + ((size_t)blockIdx.y * NROWS + row0 + t) * 4;
  po[0] = make_uint4(dd[0], dd[1], dd[2], dd[3]);
  po[1] = make_uint4(dd[4], dd[5], dd[6], dd[7]);
  po[2] = make_uint4(dd[8], dd[9], dd[10], dd[11]);
  po[3] = make_uint4(dd[12], dd[13], dd[14], dd[15]);
}

// ------- Kernel 2: merge packed partials, exact f64 re-rank, BN stats ---------
// x (density ratio) is written into dsbuf; ds_kernel transforms it in place.
__global__ __launch_bounds__(256) void merge_stats(const float4* __restrict__ pos4,
                                                   const float* __restrict__ invd,
                                                   const uint4* __restrict__ keys,
                                                   int* __restrict__ nn_idx,
                                                   float* __restrict__ dsbuf,
                                                   double* __restrict__ st) {
  int r = blockIdx.x * blockDim.x + threadIdx.x;
  int b = r >> 12, n = r & (NPTS - 1);

  unsigned top[24];
#pragma unroll
  for (int s = 0; s < 24; ++s) top[s] = 0xFFFFFFFFu;
  for (int c = 0; c < NCHUNK; ++c) {
    const uint4* ps = keys + ((size_t)c * NROWS + r) * 4;
    unsigned kk[16];
    uint4 u0 = ps[0], u1 = ps[1], u2 = ps[2], u3 = ps[3];
    kk[0]=u0.x; kk[1]=u0.y; kk[2]=u0.z; kk[3]=u0.w;
    kk[4]=u1.x; kk[5]=u1.y; kk[6]=u1.z; kk[7]=u1.w;
    kk[8]=u2.x; kk[9]=u2.y; kk[10]=u2.z; kk[11]=u2.w;
    kk[12]=u3.x; kk[13]=u3.y; kk[14]=u3.z; kk[15]=u3.w;
#pragma unroll 4
    for (int s = 0; s < 16; ++s) {
      unsigned key = kk[s];
      if (key >= top[23]) break;
#pragma unroll
      for (int q2 = 0; q2 < 24; ++q2) {
        unsigned lo = min(key, top[q2]);
        key = max(key, top[q2]);
        top[q2] = lo;
      }
    }
  }

  const float4* pb = pos4 + b * NPTS;
  float4 qp = pb[n];
  double xi = qp.x, yi = qp.y, zi = qp.z;
  double dd[16]; int ii[16];
#pragma unroll
  for (int s = 0; s < 16; ++s) { dd[s] = 1e300; ii[s] = 0; }
#pragma unroll 4
  for (int s = 0; s < 24; ++s) {
    int j = (int)(top[s] & 0xFFFu);
    float4 cj = pb[j];
    double dx = xi - (double)cj.x;
    double dy = yi - (double)cj.y;
    double dz = zi - (double)cj.z;
    double dist = dx * dx + dy * dy + dz * dz;
    if (dist < dd[15]) insert16(dist, j, dd, ii);
  }

  const float* ivb = invd + b * NPTS;
  float xv[16];
  float vmax = -1e30f;
#pragma unroll
  for (int s = 0; s < 16; ++s) {
    int j = ii[s];
    nn_idx[(size_t)r * 16 + s] = j;
    float v = ivb[j];
    xv[s] = v;
    vmax = fmaxf(vmax, v);
  }
  double sx = 0, sxx = 0;
  double l1x = 0, l1y = 0, l1z = 0;
  double lxx = 0, lyy = 0, lzz = 0, lxy = 0, lxz = 0, lyz = 0;
#pragma unroll
  for (int s = 0; s < 16; ++s) {
    float x = xv[s] / vmax;
    dsbuf[(size_t)r * 16 + s] = x;
    sx += x; sxx += (double)x * (double)x;
    int j = ii[s];
    float4 cj = pb[j];
    double lx = (double)cj.x - xi;
    double ly = (double)cj.y - yi;
    double lz = (double)cj.z - zi;
    l1x += lx; l1y += ly; l1z += lz;
    lxx += lx * lx; lyy += ly * ly; lzz += lz * lz;
    lxy += lx * ly; lxz += lx * lz; lyz += ly * lz;
  }
  wave_reduce_atomic(sx, st + 0);
  wave_reduce_atomic(sxx, st + 1);
  wave_reduce_atomic(l1x, st + 2);
  wave_reduce_atomic(l1y, st + 3);
  wave_reduce_atomic(l1z, st + 4);
  wave_reduce_atomic(lxx, st + 5);
  wave_reduce_atomic(lyy, st + 6);
  wave_reduce_atomic(lzz, st + 7);
  wave_reduce_atomic(lxy, st + 8);
  wave_reduce_atomic(lxz, st + 9);
  wave_reduce_atomic(lyz, st + 10);
}

// ---------------- Kernel 3: fold BN into affine params ------------------------
__global__ void finalize_params(const double* __restrict__ st,
                                const float* __restrict__ wn_w,
                                const float* __restrict__ wn_g,
                                const float* __restrict__ wn_be,
                                const float* __restrict__ dn_w1,
                                const float* __restrict__ dn_g1,
                                const float* __restrict__ dn_be1,
                                float* __restrict__ prm) {
  const double M = (double)NROWS * 16.0;  // 262144
  int t = threadIdx.x;
  if (t < 32) {
    double m0 = st[2] / M, m1 = st[3] / M, m2 = st[4] / M;
    double cxx = st[5] / M - m0 * m0, cyy = st[6] / M - m1 * m1, czz = st[7] / M - m2 * m2;
    double cxy = st[8] / M - m0 * m1, cxz = st[9] / M - m0 * m2, cyz = st[10] / M - m1 * m2;
    double w0 = wn_w[t * 3], w1 = wn_w[t * 3 + 1], w2 = wn_w[t * 3 + 2];
    double var = w0 * w0 * cxx + w1 * w1 * cyy + w2 * w2 * czz
               + 2.0 * (w0 * w1 * cxy + w0 * w2 * cxz + w1 * w2 * cyz);
    double alpha = (double)wn_g[t] / sqrt(var + 1e-5);
    double a0 = alpha * w0, a1 = alpha * w1, a2 = alpha * w2;
    prm[t * 3] = (float)a0; prm[t * 3 + 1] = (float)a1; prm[t * 3 + 2] = (float)a2;
    prm[96 + t] = (float)((double)wn_be[t] - (a0 * m0 + a1 * m1 + a2 * m2));
  } else if (t < 48) {
    int ch = t - 32;
    double mx = st[0] / M;
    double vx = st[1] / M - mx * mx;
    double w = dn_w1[ch];
    double alpha = (double)dn_g1[ch] * w / sqrt(w * w * vx + 1e-5);
    prm[128 + ch] = (float)alpha;
    prm[144 + ch] = (float)((double)dn_be1[ch] - alpha * mx);
  }
}

// ---------------- Kernel 5: density scale (in-place sigmoid MLP) --------------
__global__ __launch_bounds__(256) void ds_kernel(float* __restrict__ dsbuf,
                                                 const float* __restrict__ prm,
                                                 const float* __restrict__ dn_w2,
                                                 const float* __restrict__ dn_b2) {
  int r = blockIdx.x * 256 + threadIdx.x;
  float A[16], Bp[16], W2[16];
#pragma unroll
  for (int ch = 0; ch < 16; ++ch) {
    A[ch] = prm[128 + ch];
    Bp[ch] = prm[144 + ch];
    W2[ch] = dn_w2[ch];
  }
  float b2 = dn_b2[0];
#pragma unroll
  for (int k = 0; k < 16; ++k) {
    float x = dsbuf[(size_t)r * 16 + k];
    float s = b2;
#pragma unroll
    for (int ch = 0; ch < 16; ++ch) s = fmaf(W2[ch], fmaxf(fmaf(A[ch], x, Bp[ch]), 0.f), s);
    dsbuf[(size_t)r * 16 + k] = 1.f / (1.f + expf(-s));
  }
}

// ---------------- Kernel T: transpose inputs (B,C,N) f32 -> (B,N,C) bf16 ------
__global__ __launch_bounds__(256) void transpose_in(const float* __restrict__ in,
                                                    ushort* __restrict__ inT) {
  __shared__ float tile[64][68];
  int t = threadIdx.x;
  int b = blockIdx.x >> 6;
  int n0 = (blockIdx.x & 63) << 6;
  {
    int c = t >> 2, q = t & 3;
    const float* src = in + ((size_t)(b * 64 + c)) * NPTS + n0 + q * 16;
    float4 v0 = ((const float4*)src)[0];
    float4 v1 = ((const float4*)src)[1];
    float4 v2 = ((const float4*)src)[2];
    float4 v3 = ((const float4*)src)[3];
    *(float4*)&tile[c][q * 16 + 0] = v0;
    *(float4*)&tile[c][q * 16 + 4] = v1;
    *(float4*)&tile[c][q * 16 + 8] = v2;
    *(float4*)&tile[c][q * 16 + 12] = v3;
  }
  __syncthreads();
  {
    int nl = t >> 2, cq = t & 3;
    unsigned pk[8];
#pragma unroll
    for (int i = 0; i < 8; ++i) {
      float lo = tile[cq * 16 + 2 * i][nl];
      float hi = tile[cq * 16 + 2 * i + 1][nl];
      pk[i] = pk2(lo, hi);
    }
    uint4* dst = (uint4*)(inT + ((size_t)(b * NPTS + n0 + nl)) * 64 + cq * 16);
    dst[0] = make_uint4(pk[0], pk[1], pk[2], pk[3]);
    dst[1] = make_uint4(pk[4], pk[5], pk[6], pk[7]);
  }
}

// ---------------- Kernel L: pack lin_w into B-fragment order (bf16) -----------
__global__ __launch_bounds__(256) void prep_LTf(const float* __restrict__ lin_w,
                                                ushort* __restrict__ LTf) {
  int g = blockIdx.x * 256 + threadIdx.x;   // 16384
  int l = g & 63, ot = (g >> 6) & 3, s = g >> 8;
  int o = ot * 16 + (l & 15);
  const float* src = lin_w + (size_t)o * 2048 + s * 32 + (l >> 4) * 8;
  float4 u0 = ((const float4*)src)[0];
  float4 u1 = ((const float4*)src)[1];
  ((uint4*)LTf)[g] = make_uint4(pk2(u0.x, u0.y), pk2(u0.z, u0.w),
                                pk2(u1.x, u1.y), pk2(u1.z, u1.w));
}

// ---------------- Kernel A: gather + WeightNet + per-point matmul -------------
// F chunk idx = (ptLocal*64 + c)*64 + lane; lane = pl + 16*(w>>3); elems j = w&7
#define XSTR 2320   // bytes per point: 16 k-rows * 144B (128 data + 16 pad)
#define WSTR 524    // f32 per point: 16 k * 32 w + 12 pad
__global__ __launch_bounds__(256, 2) void featA(const ushort* __restrict__ inT,
                                                const float4* __restrict__ pos4,
                                                const int* __restrict__ nn_idx,
                                                const float* __restrict__ dsbuf,
                                                const float* __restrict__ prm_g,
                                                ushort* __restrict__ F,
                                                int ptBase) {
  __shared__ __align__(16) char xraw[16 * XSTR];
  __shared__ __align__(16) float wlds[16 * WSTR];
  __shared__ float prms[128];
  int t = threadIdx.x;
  int lblk = blockIdx.x;
  int blk = ptBase + lblk;
  int b = blk >> 8;
  if (t < 128) prms[t] = prm_g[t];
  __syncthreads();
  // ---- stage: thread (k = t>>4, p = t&15) ----
  {
    int k = t >> 4, p = t & 15;
    int r = blk * 16 + p;
    int n = r & (NPTS - 1);
    int j = nn_idx[(size_t)r * 16 + k];
    float4 pj = pos4[b * NPTS + j];
    float4 pn = pos4[b * NPTS + n];
    float lx = pj.x - pn.x, ly = pj.y - pn.y, lz = pj.z - pn.z;
    float ds = dsbuf[(size_t)r * 16 + k];
    const uint4* srcx = (const uint4*)(inT + ((size_t)(b * NPTS + j)) * 64);
    uint4* dstx = (uint4*)(xraw + p * XSTR + k * 144);
#pragma unroll
    for (int i = 0; i < 8; ++i) dstx[i] = srcx[i];
    float* wr = wlds + p * WSTR + k * 32;
#pragma unroll
    for (int w = 0; w < 32; ++w) {
      float v = fmaf(prms[w * 3], lx,
                fmaf(prms[w * 3 + 1], ly,
                fmaf(prms[w * 3 + 2], lz, prms[96 + w])));
      wr[w] = fmaxf(v, 0.f) * ds;
    }
  }
  __syncthreads();
  // ---- compute: thread (pl = t&15, cl = t>>4), 4 channels ----
  int pl = t & 15, cl = t >> 4;
  float acc[4][32];
#pragma unroll
  for (int ci = 0; ci < 4; ++ci)
#pragma unroll
    for (int w = 0; w < 32; ++w) acc[ci][w] = 0.f;
  const char* xrow = xraw + pl * XSTR;
  const float* wp = wlds + pl * WSTR;
#pragma unroll
  for (int kk = 0; kk < 16; ++kk) {
    unsigned xa = *(const unsigned*)(xrow + kk * 144 + cl * 4);        // ch 2cl,2cl+1
    unsigned xb = *(const unsigned*)(xrow + kk * 144 + 64 + cl * 4);   // ch 32+2cl,33+2cl (FIXED)
    float x0 = __uint_as_float(xa << 16);
    float x1 = __uint_as_float(xa & 0xFFFF0000u);
    float x2 = __uint_as_float(xb << 16);
    float x3 = __uint_as_float(xb & 0xFFFF0000u);
    float wv[32];
    const float4* wk4 = (const float4*)(wp + kk * 32);
#pragma unroll
    for (int q = 0; q < 8; ++q) *(float4*)&wv[q * 4] = wk4[q];
#pragma unroll
    for (int w = 0; w < 32; ++w) {
      float wvv = wv[w];
      acc[0][w] = fmaf(x0, wvv, acc[0][w]);
      acc[1][w] = fmaf(x1, wvv, acc[1][w]);
      acc[2][w] = fmaf(x2, wvv, acc[2][w]);
      acc[3][w] = fmaf(x3, wvv, acc[3][w]);
    }
  }
  // ---- write F fragments (chunk-local tile index) ----
  int cs[4] = {2 * cl, 2 * cl + 1, 2 * cl + 32, 2 * cl + 33};
#pragma unroll
  for (int ci = 0; ci < 4; ++ci) {
    size_t base = ((size_t)(lblk * 64 + cs[ci])) * 64;
#pragma unroll
    for (int h = 0; h < 4; ++h) {
      uint4 v = make_uint4(pk2(acc[ci][8 * h + 0], acc[ci][8 * h + 1]),
                           pk2(acc[ci][8 * h + 2], acc[ci][8 * h + 3]),
                           pk2(acc[ci][8 * h + 4], acc[ci][8 * h + 5]),
                           pk2(acc[ci][8 * h + 6], acc[ci][8 * h + 7]));
      ((uint4*)F)[base + pl + 16 * h] = v;
    }
  }
}

// ---------------- Kernel B: MFMA GEMM  out = F @ LT + bias --------------------
// Block = 32 points (2 M-tiles), 4 waves K-split, LDS reduce.
__global__ __launch_bounds__(256) void gemmB(const ushort* __restrict__ F,
                                             const ushort* __restrict__ LTf,
                                             const float* __restrict__ lin_b,
                                             float* __restrict__ out,
                                             int ptBase) {
  __shared__ f32x4 red[4][2][4][64];   // 32KB
  int t = threadIdx.x;
  int bx = blockIdx.x;
  int w = t >> 6, l = t & 63;
  int lpt0 = bx * 2, lpt1 = lpt0 + 1;
  f32x4 acc[2][4];
#pragma unroll
  for (int m = 0; m < 2; ++m)
#pragma unroll
    for (int o = 0; o < 4; ++o) acc[m][o] = (f32x4)0.f;
  const uint4* Fq = (const uint4*)F;
  const uint4* Lq = (const uint4*)LTf;
#pragma unroll 2
  for (int si = 0; si < 16; ++si) {
    int s = w * 16 + si;
    uint4 ua0 = Fq[((size_t)lpt0 * 64 + s) * 64 + l];
    uint4 ua1 = Fq[((size_t)lpt1 * 64 + s) * 64 + l];
    uint4 ub0 = Lq[(s * 4 + 0) * 64 + l];
    uint4 ub1 = Lq[(s * 4 + 1) * 64 + l];
    uint4 ub2 = Lq[(s * 4 + 2) * 64 + l];
    uint4 ub3 = Lq[(s * 4 + 3) * 64 + l];
    bf16x8 A0 = *reinterpret_cast<bf16x8*>(&ua0);
    bf16x8 A1 = *reinterpret_cast<bf16x8*>(&ua1);
    bf16x8 B0 = *reinterpret_cast<bf16x8*>(&ub0);
    bf16x8 B1 = *reinterpret_cast<bf16x8*>(&ub1);
    bf16x8 B2 = *reinterpret_cast<bf16x8*>(&ub2);
    bf16x8 B3 = *reinterpret_cast<bf16x8*>(&ub3);
    acc[0][0] = __builtin_amdgcn_mfma_f32_16x16x32_bf16(A0, B0, acc[0][0], 0, 0, 0);
    acc[0][1] = __builtin_amdgcn_mfma_f32_16x16x32_bf16(A0, B1, acc[0][1], 0, 0, 0);
    acc[0][2] = __builtin_amdgcn_mfma_f32_16x16x32_bf16(A0, B2, acc[0][2], 0, 0, 0);
    acc[0][3] = __builtin_amdgcn_mfma_f32_16x16x32_bf16(A0, B3, acc[0][3], 0, 0, 0);
    acc[1][0] = __builtin_amdgcn_mfma_f32_16x16x32_bf16(A1, B0, acc[1][0], 0, 0, 0);
    acc[1][1] = __builtin_amdgcn_mfma_f32_16x16x32_bf16(A1, B1, acc[1][1], 0, 0, 0);
    acc[1][2] = __builtin_amdgcn_mfma_f32_16x16x32_bf16(A1, B2, acc[1][2], 0, 0, 0);
    acc[1][3] = __builtin_amdgcn_mfma_f32_16x16x32_bf16(A1, B3, acc[1][3], 0, 0, 0);
  }
#pragma unroll
  for (int m = 0; m < 2; ++m)
#pragma unroll
    for (int o = 0; o < 4; ++o) red[w][m][o][l] = acc[m][o];
  __syncthreads();
  {
    int g = t >> 6;
    int mt = g >> 1, oth = (g & 1) * 2;
    int r0 = (ptBase + lpt0) * 16;
    int b = r0 >> 12;
    int n0 = r0 & (NPTS - 1);
#pragma unroll
    for (int oo = 0; oo < 2; ++oo) {
      int ot = oth + oo;
      f32x4 s = red[0][mt][ot][l] + red[1][mt][ot][l] + red[2][mt][ot][l] + red[3][mt][ot][l];
      int o = ot * 16 + (l & 15);
      float bias = lin_b[o];
      s.x += bias; s.y += bias; s.z += bias; s.w += bias;
      int nn = n0 + mt * 16 + (l >> 4) * 4;
      *(f32x4*)(out + ((size_t)(b * 64 + o)) * NPTS + nn) = s;
    }
  }
}

// ------------------------------- launch ---------------------------------------
extern "C" void kernel_launch(void* const* d_in, const int* in_sizes, int n_in,
                              void* d_out, int out_size, void* d_ws, size_t ws_size,
                              hipStream_t stream) {
  (void)in_sizes; (void)n_in; (void)out_size;
  const float* inputs = (const float*)d_in[0];
  const float* pos    = (const float*)d_in[1];
  const float* invd   = (const float*)d_in[2];
  const float* wn_w   = (const float*)d_in[3];
  const float* wn_g   = (const float*)d_in[5];
  const float* wn_be  = (const float*)d_in[6];
  const float* dn_w1  = (const float*)d_in[7];
  const float* dn_g1  = (const float*)d_in[9];
  const float* dn_be1 = (const float*)d_in[10];
  const float* dn_w2  = (const float*)d_in[11];
  const float* dn_b2  = (const float*)d_in[12];
  const float* lin_w  = (const float*)d_in[13];
  const float* lin_b  = (const float*)d_in[14];
  float* outp = (float*)d_out;

  char* ws = (char*)d_ws;
  double* stats = (double*)ws;                         // 128 B
  float*  prm   = (float*)(ws + 1024);                 // 640 B
  float4* pos4  = (float4*)(ws + 4096);                // 256 KB
  int*    nnidx = (int*)(ws + (size_t)(1u << 19));     // 1 MB   [0.5, 1.5)
  float*  dsbuf = (float*)(ws + (size_t)(3u << 19));   // 1 MB   [1.5, 2.5)
  ushort* inT   = (ushort*)(ws + (size_t)(5u << 19));  // 2 MB   [2.5, 4.5)
  ushort* LTf   = (ushort*)(ws + (size_t)(9u << 19));  // 256 KB [4.5, 4.75)
  uint4*  keys  = (uint4*)(ws + (size_t)(5u << 20));   // 16 MB  [5, 21) — dead after merge
  ushort* F     = (ushort*)(ws + (size_t)(5u << 20));  // 64/n MB, aliases keys

  // F chunking from available scratch (deterministic per environment)
  size_t avail = ws_size > (size_t)(5u << 20) ? ws_size - (size_t)(5u << 20) : 0;
  int nch;
  if (avail >= (size_t)(64u << 20)) nch = 1;
  else if (avail >= (size_t)(32u << 20)) nch = 2;
  else nch = 4;
  int tilesPer = 1024 / nch;

  hipMemsetAsync(stats, 0, 128, stream);
  pack_pos4<<<64, 256, 0, stream>>>(pos, pos4);
  transpose_in<<<256, 256, 0, stream>>>(inputs, inT);
  prep_LTf<<<64, 256, 0, stream>>>(lin_w, LTf);
  knn_partial<<<dim3(64, NCHUNK), 256, 0, stream>>>(pos4, keys);
  merge_stats<<<64, 256, 0, stream>>>(pos4, invd, keys, nnidx, dsbuf, stats);
  finalize_params<<<1, 64, 0, stream>>>(stats, wn_w, wn_g, wn_be, dn_w1, dn_g1, dn_be1, prm);
  ds_kernel<<<64, 256, 0, stream>>>(dsbuf, prm, dn_w2, dn_b2);
  for (int c = 0; c < nch; ++c) {
    featA<<<tilesPer, 256, 0, stream>>>(inT, pos4, nnidx, dsbuf, prm, F, c * tilesPer);
    gemmB<<<tilesPer / 2, 256, 0, stream>>>(F, LTf, lin_b, outp, c * tilesPer);
  }
}

// Round 5
// 248.218 us; speedup vs baseline: 2.1967x; 1.0379x over previous
//
#include <hip/hip_runtime.h>
#include <math.h>

// Problem constants
#define NB 4
#define NC 64
#define NPTS 4096
#define NROWS (NB*NPTS)      // 16384
#define NCHUNK 16            // KNN candidate chunks
#define CHSZ (NPTS/NCHUNK)   // 256

typedef __attribute__((ext_vector_type(4))) float f32x4;
typedef __bf16 bf16x8 __attribute__((ext_vector_type(8)));

__device__ __forceinline__ ushort f2bf(float f) {
  unsigned u = __float_as_uint(f);
  u = (u + 0x7FFFu + ((u >> 16) & 1u)) >> 16;   // RNE
  return (ushort)u;
}
__device__ __forceinline__ unsigned pk2(float lo, float hi) {
  return (unsigned)f2bf(lo) | ((unsigned)f2bf(hi) << 16);
}

// ---------------- top-16 insertion (sorted ascending, dd[15]=max) -------------
__device__ __forceinline__ void insert16(double dist, int j, double (&dd)[16], int (&ii)[16]) {
  double cd = dist; int ci = j;
#pragma unroll
  for (int s = 0; s < 16; ++s) {
    double od = dd[s]; int oi = ii[s];
    bool c = cd < od;
    dd[s] = c ? cd : od;
    ii[s] = c ? ci : oi;
    cd = c ? od : cd;
    ci = c ? oi : ci;
  }
}

__device__ __forceinline__ void wave_reduce_atomic(double v, double* dst) {
#pragma unroll
  for (int off = 32; off; off >>= 1) v += __shfl_down(v, off, 64);
  if ((threadIdx.x & 63) == 0) atomicAdd(dst, v);
}

// ---------------- Kernel 0: pack positions as float4 --------------------------
__global__ __launch_bounds__(256) void pack_pos4(const float* __restrict__ pos,
                                                 float4* __restrict__ pos4) {
  int g = blockIdx.x * 256 + threadIdx.x;   // 4*4096 total
  int b = g >> 12, n = g & (NPTS - 1);
  const float* pb = pos + b * 3 * NPTS;
  pos4[g] = make_float4(pb[n], pb[NPTS + n], pb[2 * NPTS + n], 0.f);
}

// ---------------- Kernel 1: partial KNN over candidate chunk ------------------
__global__ __launch_bounds__(256) void knn_partial(const float4* __restrict__ pos4,
                                                   uint4* __restrict__ keys) {
  __shared__ float4 cand[CHSZ];
  int t = threadIdx.x;
  int row0 = blockIdx.x * 256;
  int b = row0 >> 12;
  int j0 = blockIdx.y * CHSZ;
  const float4* pb = pos4 + b * NPTS;
  cand[t] = pb[j0 + t];
  __syncthreads();
  float4 q = pb[(row0 + t) & (NPTS - 1)];
  unsigned dd[16];
#pragma unroll
  for (int s = 0; s < 16; ++s) dd[s] = 0xFFFFFFFFu;
#pragma unroll 4
  for (int jj = 0; jj < CHSZ; ++jj) {
    float4 c = cand[jj];
    float dx = q.x - c.x, dy = q.y - c.y, dz = q.z - c.z;
    float d = fmaf(dx, dx, fmaf(dy, dy, dz * dz));
    unsigned key = (__float_as_uint(d) & 0xFFFFF000u) | (unsigned)(j0 + jj);
#pragma unroll
    for (int s = 0; s < 16; ++s) {
      unsigned lo = min(key, dd[s]);
      key = max(key, dd[s]);
      dd[s] = lo;
    }
  }
  uint4* po = keys + ((size_t)blockIdx.y * NROWS + row0 + t) * 4;
  po[0] = make_uint4(dd[0], dd[1], dd[2], dd[3]);
  po[1] = make_uint4(dd[4], dd[5], dd[6], dd[7]);
  po[2] = make_uint4(dd[8], dd[9], dd[10], dd[11]);
  po[3] = make_uint4(dd[12], dd[13], dd[14], dd[15]);
}

// ------- Kernel 2: merge packed partials, exact f64 re-rank, BN stats ---------
__global__ __launch_bounds__(256) void merge_stats(const float4* __restrict__ pos4,
                                                   const float* __restrict__ invd,
                                                   const uint4* __restrict__ keys,
                                                   int* __restrict__ nn_idx,
                                                   float* __restrict__ dsbuf,
                                                   double* __restrict__ st) {
  int r = blockIdx.x * blockDim.x + threadIdx.x;
  int b = r >> 12, n = r & (NPTS - 1);

  unsigned top[24];
#pragma unroll
  for (int s = 0; s < 24; ++s) top[s] = 0xFFFFFFFFu;
  for (int c = 0; c < NCHUNK; ++c) {
    const uint4* ps = keys + ((size_t)c * NROWS + r) * 4;
    unsigned kk[16];
    uint4 u0 = ps[0], u1 = ps[1], u2 = ps[2], u3 = ps[3];
    kk[0]=u0.x; kk[1]=u0.y; kk[2]=u0.z; kk[3]=u0.w;
    kk[4]=u1.x; kk[5]=u1.y; kk[6]=u1.z; kk[7]=u1.w;
    kk[8]=u2.x; kk[9]=u2.y; kk[10]=u2.z; kk[11]=u2.w;
    kk[12]=u3.x; kk[13]=u3.y; kk[14]=u3.z; kk[15]=u3.w;
#pragma unroll 4
    for (int s = 0; s < 16; ++s) {
      unsigned key = kk[s];
      if (key >= top[23]) break;
#pragma unroll
      for (int q2 = 0; q2 < 24; ++q2) {
        unsigned lo = min(key, top[q2]);
        key = max(key, top[q2]);
        top[q2] = lo;
      }
    }
  }

  const float4* pb = pos4 + b * NPTS;
  float4 qp = pb[n];
  double xi = qp.x, yi = qp.y, zi = qp.z;
  double dd[16]; int ii[16];
#pragma unroll
  for (int s = 0; s < 16; ++s) { dd[s] = 1e300; ii[s] = 0; }
#pragma unroll 4
  for (int s = 0; s < 24; ++s) {
    int j = (int)(top[s] & 0xFFFu);
    float4 cj = pb[j];
    double dx = xi - (double)cj.x;
    double dy = yi - (double)cj.y;
    double dz = zi - (double)cj.z;
    double dist = dx * dx + dy * dy + dz * dz;
    if (dist < dd[15]) insert16(dist, j, dd, ii);
  }

  const float* ivb = invd + b * NPTS;
  float xv[16];
  float vmax = -1e30f;
#pragma unroll
  for (int s = 0; s < 16; ++s) {
    int j = ii[s];
    nn_idx[(size_t)r * 16 + s] = j;
    float v = ivb[j];
    xv[s] = v;
    vmax = fmaxf(vmax, v);
  }
  double sx = 0, sxx = 0;
  double l1x = 0, l1y = 0, l1z = 0;
  double lxx = 0, lyy = 0, lzz = 0, lxy = 0, lxz = 0, lyz = 0;
#pragma unroll
  for (int s = 0; s < 16; ++s) {
    float x = xv[s] / vmax;
    dsbuf[(size_t)r * 16 + s] = x;
    sx += x; sxx += (double)x * (double)x;
    int j = ii[s];
    float4 cj = pb[j];
    double lx = (double)cj.x - xi;
    double ly = (double)cj.y - yi;
    double lz = (double)cj.z - zi;
    l1x += lx; l1y += ly; l1z += lz;
    lxx += lx * lx; lyy += ly * ly; lzz += lz * lz;
    lxy += lx * ly; lxz += lx * lz; lyz += ly * lz;
  }
  wave_reduce_atomic(sx, st + 0);
  wave_reduce_atomic(sxx, st + 1);
  wave_reduce_atomic(l1x, st + 2);
  wave_reduce_atomic(l1y, st + 3);
  wave_reduce_atomic(l1z, st + 4);
  wave_reduce_atomic(lxx, st + 5);
  wave_reduce_atomic(lyy, st + 6);
  wave_reduce_atomic(lzz, st + 7);
  wave_reduce_atomic(lxy, st + 8);
  wave_reduce_atomic(lxz, st + 9);
  wave_reduce_atomic(lyz, st + 10);
}

// ---------------- Kernel 3: fold BN into affine params ------------------------
__global__ void finalize_params(const double* __restrict__ st,
                                const float* __restrict__ wn_w,
                                const float* __restrict__ wn_g,
                                const float* __restrict__ wn_be,
                                const float* __restrict__ dn_w1,
                                const float* __restrict__ dn_g1,
                                const float* __restrict__ dn_be1,
                                float* __restrict__ prm) {
  const double M = (double)NROWS * 16.0;  // 262144
  int t = threadIdx.x;
  if (t < 32) {
    double m0 = st[2] / M, m1 = st[3] / M, m2 = st[4] / M;
    double cxx = st[5] / M - m0 * m0, cyy = st[6] / M - m1 * m1, czz = st[7] / M - m2 * m2;
    double cxy = st[8] / M - m0 * m1, cxz = st[9] / M - m0 * m2, cyz = st[10] / M - m1 * m2;
    double w0 = wn_w[t * 3], w1 = wn_w[t * 3 + 1], w2 = wn_w[t * 3 + 2];
    double var = w0 * w0 * cxx + w1 * w1 * cyy + w2 * w2 * czz
               + 2.0 * (w0 * w1 * cxy + w0 * w2 * cxz + w1 * w2 * cyz);
    double alpha = (double)wn_g[t] / sqrt(var + 1e-5);
    double a0 = alpha * w0, a1 = alpha * w1, a2 = alpha * w2;
    prm[t * 3] = (float)a0; prm[t * 3 + 1] = (float)a1; prm[t * 3 + 2] = (float)a2;
    prm[96 + t] = (float)((double)wn_be[t] - (a0 * m0 + a1 * m1 + a2 * m2));
  } else if (t < 48) {
    int ch = t - 32;
    double mx = st[0] / M;
    double vx = st[1] / M - mx * mx;
    double w = dn_w1[ch];
    double alpha = (double)dn_g1[ch] * w / sqrt(w * w * vx + 1e-5);
    prm[128 + ch] = (float)alpha;
    prm[144 + ch] = (float)((double)dn_be1[ch] - alpha * mx);
  }
}

// ---------------- Kernel 5: density scale (in-place sigmoid MLP) --------------
__global__ __launch_bounds__(256) void ds_kernel(float* __restrict__ dsbuf,
                                                 const float* __restrict__ prm,
                                                 const float* __restrict__ dn_w2,
                                                 const float* __restrict__ dn_b2) {
  int r = blockIdx.x * 256 + threadIdx.x;
  float A[16], Bp[16], W2[16];
#pragma unroll
  for (int ch = 0; ch < 16; ++ch) {
    A[ch] = prm[128 + ch];
    Bp[ch] = prm[144 + ch];
    W2[ch] = dn_w2[ch];
  }
  float b2 = dn_b2[0];
#pragma unroll
  for (int k = 0; k < 16; ++k) {
    float x = dsbuf[(size_t)r * 16 + k];
    float s = b2;
#pragma unroll
    for (int ch = 0; ch < 16; ++ch) s = fmaf(W2[ch], fmaxf(fmaf(A[ch], x, Bp[ch]), 0.f), s);
    dsbuf[(size_t)r * 16 + k] = 1.f / (1.f + expf(-s));
  }
}

// ---------------- Kernel T: transpose inputs (B,C,N) f32 -> (B,N,C) bf16 ------
__global__ __launch_bounds__(256) void transpose_in(const float* __restrict__ in,
                                                    ushort* __restrict__ inT) {
  __shared__ float tile[64][68];
  int t = threadIdx.x;
  int b = blockIdx.x >> 6;
  int n0 = (blockIdx.x & 63) << 6;
  {
    int c = t >> 2, q = t & 3;
    const float* src = in + ((size_t)(b * 64 + c)) * NPTS + n0 + q * 16;
    float4 v0 = ((const float4*)src)[0];
    float4 v1 = ((const float4*)src)[1];
    float4 v2 = ((const float4*)src)[2];
    float4 v3 = ((const float4*)src)[3];
    *(float4*)&tile[c][q * 16 + 0] = v0;
    *(float4*)&tile[c][q * 16 + 4] = v1;
    *(float4*)&tile[c][q * 16 + 8] = v2;
    *(float4*)&tile[c][q * 16 + 12] = v3;
  }
  __syncthreads();
  {
    int nl = t >> 2, cq = t & 3;
    unsigned pk[8];
#pragma unroll
    for (int i = 0; i < 8; ++i) {
      float lo = tile[cq * 16 + 2 * i][nl];
      float hi = tile[cq * 16 + 2 * i + 1][nl];
      pk[i] = pk2(lo, hi);
    }
    uint4* dst = (uint4*)(inT + ((size_t)(b * NPTS + n0 + nl)) * 64 + cq * 16);
    dst[0] = make_uint4(pk[0], pk[1], pk[2], pk[3]);
    dst[1] = make_uint4(pk[4], pk[5], pk[6], pk[7]);
  }
}

// ---------------- Kernel L: pack lin_w into B-fragment order (bf16) -----------
__global__ __launch_bounds__(256) void prep_LTf(const float* __restrict__ lin_w,
                                                ushort* __restrict__ LTf) {
  int g = blockIdx.x * 256 + threadIdx.x;   // 16384
  int l = g & 63, ot = (g >> 6) & 3, s = g >> 8;
  int o = ot * 16 + (l & 15);
  const float* src = lin_w + (size_t)o * 2048 + s * 32 + (l >> 4) * 8;
  float4 u0 = ((const float4*)src)[0];
  float4 u1 = ((const float4*)src)[1];
  ((uint4*)LTf)[g] = make_uint4(pk2(u0.x, u0.y), pk2(u0.z, u0.w),
                                pk2(u1.x, u1.y), pk2(u1.z, u1.w));
}

// ------- Fused kernel: gather + WeightNet + per-point matmul + MFMA GEMM ------
// Block = 16 points. Phase 1: stage gathers + W' rows. Phase 2: feat in regs.
// Phase 3: feat -> LDS as MFMA A-frags (aliases phase-1 LDS). Phase 4: each
// wave does K=2048 MFMA GEMM for one 16-wide output tile. No global F buffer.
#define XSTR 2320   // bytes per point: 16 k-rows * 144B (128 data + 16 pad)
#define WSTR 524    // f32 per point: 16 k * 32 w + 12 pad
__global__ __launch_bounds__(256, 2) void fused(const ushort* __restrict__ inT,
                                                const float4* __restrict__ pos4,
                                                const int* __restrict__ nn_idx,
                                                const float* __restrict__ dsbuf,
                                                const float* __restrict__ prm_g,
                                                const ushort* __restrict__ LTf,
                                                const float* __restrict__ lin_b,
                                                float* __restrict__ out) {
  __shared__ __align__(16) char smem[16 * XSTR + 16 * WSTR * 4];  // 70656 B
  __shared__ float prms[128];
  char* xraw = smem;
  float* wlds = (float*)(smem + 16 * XSTR);
  int t = threadIdx.x;
  int blk = blockIdx.x;          // 1024 tiles of 16 points
  int b = blk >> 8;
  int n0 = (blk & 255) << 4;
  if (t < 128) prms[t] = prm_g[t];
  __syncthreads();
  // ---- phase 1: stage. thread (k = t>>4, p = t&15) ----
  {
    int k = t >> 4, p = t & 15;
    int r = blk * 16 + p;
    int n = n0 + p;
    int j = nn_idx[(size_t)r * 16 + k];
    float4 pj = pos4[b * NPTS + j];
    float4 pn = pos4[b * NPTS + n];
    float lx = pj.x - pn.x, ly = pj.y - pn.y, lz = pj.z - pn.z;
    float ds = dsbuf[(size_t)r * 16 + k];
    const uint4* srcx = (const uint4*)(inT + ((size_t)(b * NPTS + j)) * 64);
    uint4* dstx = (uint4*)(xraw + p * XSTR + k * 144);
#pragma unroll
    for (int i = 0; i < 8; ++i) dstx[i] = srcx[i];
    float* wr = wlds + p * WSTR + k * 32;
#pragma unroll
    for (int w = 0; w < 32; ++w) {
      float v = fmaf(prms[w * 3], lx,
                fmaf(prms[w * 3 + 1], ly,
                fmaf(prms[w * 3 + 2], lz, prms[96 + w])));
      wr[w] = fmaxf(v, 0.f) * ds;
    }
  }
  __syncthreads();
  // ---- phase 2: feat in registers. thread (pl = t&15, cl = t>>4) ----
  int pl = t & 15, cl = t >> 4;
  float acc[4][32];
#pragma unroll
  for (int ci = 0; ci < 4; ++ci)
#pragma unroll
    for (int w = 0; w < 32; ++w) acc[ci][w] = 0.f;
  {
    const char* xrow = xraw + pl * XSTR;
    const float* wp = wlds + pl * WSTR;
#pragma unroll
    for (int kk = 0; kk < 16; ++kk) {
      unsigned xa = *(const unsigned*)(xrow + kk * 144 + cl * 4);        // ch 2cl,2cl+1
      unsigned xb = *(const unsigned*)(xrow + kk * 144 + 64 + cl * 4);   // ch 32+2cl,33+2cl
      float x0 = __uint_as_float(xa << 16);
      float x1 = __uint_as_float(xa & 0xFFFF0000u);
      float x2 = __uint_as_float(xb << 16);
      float x3 = __uint_as_float(xb & 0xFFFF0000u);
      float wv[32];
      const float4* wk4 = (const float4*)(wp + kk * 32);
#pragma unroll
      for (int q = 0; q < 8; ++q) *(float4*)&wv[q * 4] = wk4[q];
#pragma unroll
      for (int w = 0; w < 32; ++w) {
        float wvv = wv[w];
        acc[0][w] = fmaf(x0, wvv, acc[0][w]);
        acc[1][w] = fmaf(x1, wvv, acc[1][w]);
        acc[2][w] = fmaf(x2, wvv, acc[2][w]);
        acc[3][w] = fmaf(x3, wvv, acc[3][w]);
      }
    }
  }
  __syncthreads();   // everyone done reading xraw/wlds
  // ---- phase 3: write A-frags (bf16) over the staging LDS (64 KB) ----
  // k-step s = c index; lane = pl + 16*(w>>3); elems j = w&7; k = s*32 + w
  uint4* aq = (uint4*)smem;
  {
    int cs[4] = {2 * cl, 2 * cl + 1, 32 + 2 * cl, 33 + 2 * cl};
#pragma unroll
    for (int ci = 0; ci < 4; ++ci) {
#pragma unroll
      for (int h = 0; h < 4; ++h) {
        aq[cs[ci] * 64 + pl + 16 * h] =
            make_uint4(pk2(acc[ci][8 * h + 0], acc[ci][8 * h + 1]),
                       pk2(acc[ci][8 * h + 2], acc[ci][8 * h + 3]),
                       pk2(acc[ci][8 * h + 4], acc[ci][8 * h + 5]),
                       pk2(acc[ci][8 * h + 6], acc[ci][8 * h + 7]));
      }
    }
  }
  __syncthreads();
  // ---- phase 4: MFMA GEMM. wave wv owns output tile ot=wv, full K ----
  {
    int wv = t >> 6, l = t & 63;
    const uint4* Lq = (const uint4*)LTf;
    f32x4 cacc = (f32x4)0.f;
#pragma unroll 4
    for (int s = 0; s < 64; ++s) {
      uint4 ua = aq[s * 64 + l];
      uint4 ub = Lq[(s * 4 + wv) * 64 + l];
      bf16x8 A = *reinterpret_cast<bf16x8*>(&ua);
      bf16x8 B = *reinterpret_cast<bf16x8*>(&ub);
      cacc = __builtin_amdgcn_mfma_f32_16x16x32_bf16(A, B, cacc, 0, 0, 0);
    }
    int o = wv * 16 + (l & 15);
    float bias = lin_b[o];
    cacc.x += bias; cacc.y += bias; cacc.z += bias; cacc.w += bias;
    *(f32x4*)(out + ((size_t)(b * 64 + o)) * NPTS + n0 + (l >> 4) * 4) = cacc;
  }
}

// ------------------------------- launch ---------------------------------------
extern "C" void kernel_launch(void* const* d_in, const int* in_sizes, int n_in,
                              void* d_out, int out_size, void* d_ws, size_t ws_size,
                              hipStream_t stream) {
  (void)in_sizes; (void)n_in; (void)out_size; (void)ws_size;
  const float* inputs = (const float*)d_in[0];
  const float* pos    = (const float*)d_in[1];
  const float* invd   = (const float*)d_in[2];
  const float* wn_w   = (const float*)d_in[3];
  const float* wn_g   = (const float*)d_in[5];
  const float* wn_be  = (const float*)d_in[6];
  const float* dn_w1  = (const float*)d_in[7];
  const float* dn_g1  = (const float*)d_in[9];
  const float* dn_be1 = (const float*)d_in[10];
  const float* dn_w2  = (const float*)d_in[11];
  const float* dn_b2  = (const float*)d_in[12];
  const float* lin_w  = (const float*)d_in[13];
  const float* lin_b  = (const float*)d_in[14];
  float* outp = (float*)d_out;

  char* ws = (char*)d_ws;
  double* stats = (double*)ws;                         // 128 B
  float*  prm   = (float*)(ws + 1024);                 // 640 B
  float4* pos4  = (float4*)(ws + 4096);                // 256 KB
  int*    nnidx = (int*)(ws + (size_t)(1u << 19));     // 1 MB   [0.5, 1.5)
  float*  dsbuf = (float*)(ws + (size_t)(3u << 19));   // 1 MB   [1.5, 2.5)
  ushort* inT   = (ushort*)(ws + (size_t)(5u << 19));  // 2 MB   [2.5, 4.5)
  ushort* LTf   = (ushort*)(ws + (size_t)(9u << 19));  // 256 KB [4.5, 4.75)
  uint4*  keys  = (uint4*)(ws + (size_t)(5u << 20));   // 16 MB  [5, 21)

  hipMemsetAsync(stats, 0, 128, stream);
  pack_pos4<<<64, 256, 0, stream>>>(pos, pos4);
  transpose_in<<<256, 256, 0, stream>>>(inputs, inT);
  prep_LTf<<<64, 256, 0, stream>>>(lin_w, LTf);
  knn_partial<<<dim3(64, NCHUNK), 256, 0, stream>>>(pos4, keys);
  merge_stats<<<64, 256, 0, stream>>>(pos4, invd, keys, nnidx, dsbuf, stats);
  finalize_params<<<1, 64, 0, stream>>>(stats, wn_w, wn_g, wn_be, dn_w1, dn_g1, dn_be1, prm);
  ds_kernel<<<64, 256, 0, stream>>>(dsbuf, prm, dn_w2, dn_b2);
  fused<<<1024, 256, 0, stream>>>(inT, pos4, nnidx, dsbuf, prm, LTf, lin_b, outp);
}

// Round 6
// 190.242 us; speedup vs baseline: 2.8661x; 1.3048x over previous
//
#include <hip/hip_runtime.h>
#include <math.h>

// Problem constants
#define NB 4
#define NC 64
#define NPTS 4096
#define NROWS (NB*NPTS)      // 16384
#define NCHUNK 16            // KNN candidate chunks
#define CHSZ (NPTS/NCHUNK)   // 256

typedef __attribute__((ext_vector_type(4))) float f32x4;
typedef __bf16 bf16x8 __attribute__((ext_vector_type(8)));

__device__ __forceinline__ ushort f2bf(float f) {
  unsigned u = __float_as_uint(f);
  u = (u + 0x7FFFu + ((u >> 16) & 1u)) >> 16;   // RNE
  return (ushort)u;
}
__device__ __forceinline__ unsigned pk2(float lo, float hi) {
  return (unsigned)f2bf(lo) | ((unsigned)f2bf(hi) << 16);
}

// ---------------- top-16 insertion (sorted ascending, dd[15]=max) -------------
__device__ __forceinline__ void insert16(double dist, int j, double (&dd)[16], int (&ii)[16]) {
  double cd = dist; int ci = j;
#pragma unroll
  for (int s = 0; s < 16; ++s) {
    double od = dd[s]; int oi = ii[s];
    bool c = cd < od;
    dd[s] = c ? cd : od;
    ii[s] = c ? ci : oi;
    cd = c ? od : cd;
    ci = c ? oi : ci;
  }
}

__device__ __forceinline__ void wave_reduce_atomic(double v, double* dst) {
#pragma unroll
  for (int off = 32; off; off >>= 1) v += __shfl_down(v, off, 64);
  if ((threadIdx.x & 63) == 0) atomicAdd(dst, v);
}

// ---------------- Kernel 0: pack positions as float4 --------------------------
__global__ __launch_bounds__(256) void pack_pos4(const float* __restrict__ pos,
                                                 float4* __restrict__ pos4) {
  int g = blockIdx.x * 256 + threadIdx.x;   // 4*4096 total
  int b = g >> 12, n = g & (NPTS - 1);
  const float* pb = pos + b * 3 * NPTS;
  pos4[g] = make_float4(pb[n], pb[NPTS + n], pb[2 * NPTS + n], 0.f);
}

// ---------------- Kernel 1: partial KNN over candidate chunk ------------------
__global__ __launch_bounds__(256) void knn_partial(const float4* __restrict__ pos4,
                                                   uint4* __restrict__ keys) {
  __shared__ float4 cand[CHSZ];
  int t = threadIdx.x;
  int row0 = blockIdx.x * 256;
  int b = row0 >> 12;
  int j0 = blockIdx.y * CHSZ;
  const float4* pb = pos4 + b * NPTS;
  cand[t] = pb[j0 + t];
  __syncthreads();
  float4 q = pb[(row0 + t) & (NPTS - 1)];
  unsigned dd[16];
#pragma unroll
  for (int s = 0; s < 16; ++s) dd[s] = 0xFFFFFFFFu;
#pragma unroll 4
  for (int jj = 0; jj < CHSZ; ++jj) {
    float4 c = cand[jj];
    float dx = q.x - c.x, dy = q.y - c.y, dz = q.z - c.z;
    float d = fmaf(dx, dx, fmaf(dy, dy, dz * dz));
    unsigned key = (__float_as_uint(d) & 0xFFFFF000u) | (unsigned)(j0 + jj);
#pragma unroll
    for (int s = 0; s < 16; ++s) {
      unsigned lo = min(key, dd[s]);
      key = max(key, dd[s]);
      dd[s] = lo;
    }
  }
  uint4* po = keys + ((size_t)blockIdx.y * NROWS + row0 + t) * 4;
  po[0] = make_uint4(dd[0], dd[1], dd[2], dd[3]);
  po[1] = make_uint4(dd[4], dd[5], dd[6], dd[7]);
  po[2] = make_uint4(dd[8], dd[9], dd[10], dd[11]);
  po[3] = make_uint4(dd[12], dd[13], dd[14], dd[15]);
}

// ------- Kernel 2: merge packed partials, exact f64 re-rank, BN stats ---------
__global__ __launch_bounds__(256) void merge_stats(const float4* __restrict__ pos4,
                                                   const float* __restrict__ invd,
                                                   const uint4* __restrict__ keys,
                                                   int* __restrict__ nn_idx,
                                                   float* __restrict__ dsbuf,
                                                   double* __restrict__ st) {
  int r = blockIdx.x * blockDim.x + threadIdx.x;
  int b = r >> 12, n = r & (NPTS - 1);

  unsigned top[24];
#pragma unroll
  for (int s = 0; s < 24; ++s) top[s] = 0xFFFFFFFFu;
  for (int c = 0; c < NCHUNK; ++c) {
    const uint4* ps = keys + ((size_t)c * NROWS + r) * 4;
    unsigned kk[16];
    uint4 u0 = ps[0], u1 = ps[1], u2 = ps[2], u3 = ps[3];
    kk[0]=u0.x; kk[1]=u0.y; kk[2]=u0.z; kk[3]=u0.w;
    kk[4]=u1.x; kk[5]=u1.y; kk[6]=u1.z; kk[7]=u1.w;
    kk[8]=u2.x; kk[9]=u2.y; kk[10]=u2.z; kk[11]=u2.w;
    kk[12]=u3.x; kk[13]=u3.y; kk[14]=u3.z; kk[15]=u3.w;
#pragma unroll 4
    for (int s = 0; s < 16; ++s) {
      unsigned key = kk[s];
      if (key >= top[23]) break;
#pragma unroll
      for (int q2 = 0; q2 < 24; ++q2) {
        unsigned lo = min(key, top[q2]);
        key = max(key, top[q2]);
        top[q2] = lo;
      }
    }
  }

  const float4* pb = pos4 + b * NPTS;
  float4 qp = pb[n];
  double xi = qp.x, yi = qp.y, zi = qp.z;
  double dd[16]; int ii[16];
#pragma unroll
  for (int s = 0; s < 16; ++s) { dd[s] = 1e300; ii[s] = 0; }
#pragma unroll 4
  for (int s = 0; s < 24; ++s) {
    int j = (int)(top[s] & 0xFFFu);
    float4 cj = pb[j];
    double dx = xi - (double)cj.x;
    double dy = yi - (double)cj.y;
    double dz = zi - (double)cj.z;
    double dist = dx * dx + dy * dy + dz * dz;
    if (dist < dd[15]) insert16(dist, j, dd, ii);
  }

  const float* ivb = invd + b * NPTS;
  float xv[16];
  float vmax = -1e30f;
#pragma unroll
  for (int s = 0; s < 16; ++s) {
    int j = ii[s];
    nn_idx[(size_t)r * 16 + s] = j;
    float v = ivb[j];
    xv[s] = v;
    vmax = fmaxf(vmax, v);
  }
  double sx = 0, sxx = 0;
  double l1x = 0, l1y = 0, l1z = 0;
  double lxx = 0, lyy = 0, lzz = 0, lxy = 0, lxz = 0, lyz = 0;
#pragma unroll
  for (int s = 0; s < 16; ++s) {
    float x = xv[s] / vmax;
    dsbuf[(size_t)r * 16 + s] = x;
    sx += x; sxx += (double)x * (double)x;
    int j = ii[s];
    float4 cj = pb[j];
    double lx = (double)cj.x - xi;
    double ly = (double)cj.y - yi;
    double lz = (double)cj.z - zi;
    l1x += lx; l1y += ly; l1z += lz;
    lxx += lx * lx; lyy += ly * ly; lzz += lz * lz;
    lxy += lx * ly; lxz += lx * lz; lyz += ly * lz;
  }
  wave_reduce_atomic(sx, st + 0);
  wave_reduce_atomic(sxx, st + 1);
  wave_reduce_atomic(l1x, st + 2);
  wave_reduce_atomic(l1y, st + 3);
  wave_reduce_atomic(l1z, st + 4);
  wave_reduce_atomic(lxx, st + 5);
  wave_reduce_atomic(lyy, st + 6);
  wave_reduce_atomic(lzz, st + 7);
  wave_reduce_atomic(lxy, st + 8);
  wave_reduce_atomic(lxz, st + 9);
  wave_reduce_atomic(lyz, st + 10);
}

// ---------------- Kernel 3: fold BN into affine params ------------------------
__global__ void finalize_params(const double* __restrict__ st,
                                const float* __restrict__ wn_w,
                                const float* __restrict__ wn_g,
                                const float* __restrict__ wn_be,
                                const float* __restrict__ dn_w1,
                                const float* __restrict__ dn_g1,
                                const float* __restrict__ dn_be1,
                                float* __restrict__ prm) {
  const double M = (double)NROWS * 16.0;  // 262144
  int t = threadIdx.x;
  if (t < 32) {
    double m0 = st[2] / M, m1 = st[3] / M, m2 = st[4] / M;
    double cxx = st[5] / M - m0 * m0, cyy = st[6] / M - m1 * m1, czz = st[7] / M - m2 * m2;
    double cxy = st[8] / M - m0 * m1, cxz = st[9] / M - m0 * m2, cyz = st[10] / M - m1 * m2;
    double w0 = wn_w[t * 3], w1 = wn_w[t * 3 + 1], w2 = wn_w[t * 3 + 2];
    double var = w0 * w0 * cxx + w1 * w1 * cyy + w2 * w2 * czz
               + 2.0 * (w0 * w1 * cxy + w0 * w2 * cxz + w1 * w2 * cyz);
    double alpha = (double)wn_g[t] / sqrt(var + 1e-5);
    double a0 = alpha * w0, a1 = alpha * w1, a2 = alpha * w2;
    prm[t * 3] = (float)a0; prm[t * 3 + 1] = (float)a1; prm[t * 3 + 2] = (float)a2;
    prm[96 + t] = (float)((double)wn_be[t] - (a0 * m0 + a1 * m1 + a2 * m2));
  } else if (t < 48) {
    int ch = t - 32;
    double mx = st[0] / M;
    double vx = st[1] / M - mx * mx;
    double w = dn_w1[ch];
    double alpha = (double)dn_g1[ch] * w / sqrt(w * w * vx + 1e-5);
    prm[128 + ch] = (float)alpha;
    prm[144 + ch] = (float)((double)dn_be1[ch] - alpha * mx);
  }
}

// ---------------- Kernel 5: density scale (in-place sigmoid MLP) --------------
__global__ __launch_bounds__(256) void ds_kernel(float* __restrict__ dsbuf,
                                                 const float* __restrict__ prm,
                                                 const float* __restrict__ dn_w2,
                                                 const float* __restrict__ dn_b2) {
  int r = blockIdx.x * 256 + threadIdx.x;
  float A[16], Bp[16], W2[16];
#pragma unroll
  for (int ch = 0; ch < 16; ++ch) {
    A[ch] = prm[128 + ch];
    Bp[ch] = prm[144 + ch];
    W2[ch] = dn_w2[ch];
  }
  float b2 = dn_b2[0];
#pragma unroll
  for (int k = 0; k < 16; ++k) {
    float x = dsbuf[(size_t)r * 16 + k];
    float s = b2;
#pragma unroll
    for (int ch = 0; ch < 16; ++ch) s = fmaf(W2[ch], fmaxf(fmaf(A[ch], x, Bp[ch]), 0.f), s);
    dsbuf[(size_t)r * 16 + k] = 1.f / (1.f + expf(-s));
  }
}

// ---------------- Kernel T: transpose inputs (B,C,N) f32 -> (B,N,C) bf16 ------
__global__ __launch_bounds__(256) void transpose_in(const float* __restrict__ in,
                                                    ushort* __restrict__ inT) {
  __shared__ float tile[64][68];
  int t = threadIdx.x;
  int b = blockIdx.x >> 6;
  int n0 = (blockIdx.x & 63) << 6;
  {
    int c = t >> 2, q = t & 3;
    const float* src = in + ((size_t)(b * 64 + c)) * NPTS + n0 + q * 16;
    float4 v0 = ((const float4*)src)[0];
    float4 v1 = ((const float4*)src)[1];
    float4 v2 = ((const float4*)src)[2];
    float4 v3 = ((const float4*)src)[3];
    *(float4*)&tile[c][q * 16 + 0] = v0;
    *(float4*)&tile[c][q * 16 + 4] = v1;
    *(float4*)&tile[c][q * 16 + 8] = v2;
    *(float4*)&tile[c][q * 16 + 12] = v3;
  }
  __syncthreads();
  {
    int nl = t >> 2, cq = t & 3;
    unsigned pk[8];
#pragma unroll
    for (int i = 0; i < 8; ++i) {
      float lo = tile[cq * 16 + 2 * i][nl];
      float hi = tile[cq * 16 + 2 * i + 1][nl];
      pk[i] = pk2(lo, hi);
    }
    uint4* dst = (uint4*)(inT + ((size_t)(b * NPTS + n0 + nl)) * 64 + cq * 16);
    dst[0] = make_uint4(pk[0], pk[1], pk[2], pk[3]);
    dst[1] = make_uint4(pk[4], pk[5], pk[6], pk[7]);
  }
}

// ---------------- Kernel L: pack lin_w into B-fragment order (bf16) -----------
__global__ __launch_bounds__(256) void prep_LTf(const float* __restrict__ lin_w,
                                                ushort* __restrict__ LTf) {
  int g = blockIdx.x * 256 + threadIdx.x;   // 16384
  int l = g & 63, ot = (g >> 6) & 3, s = g >> 8;
  int o = ot * 16 + (l & 15);
  const float* src = lin_w + (size_t)o * 2048 + s * 32 + (l >> 4) * 8;
  float4 u0 = ((const float4*)src)[0];
  float4 u1 = ((const float4*)src)[1];
  ((uint4*)LTf)[g] = make_uint4(pk2(u0.x, u0.y), pk2(u0.z, u0.w),
                                pk2(u1.x, u1.y), pk2(u1.z, u1.w));
}

// ------- Fused kernel: gather + WeightNet + per-point matmul + MFMA GEMM ------
// Phase 2 uses ONLY named f32x4 registers (no local arrays -> no scratch).
#define XSTR 2320   // bytes per point: 16 k-rows * 144B (128 data + 16 pad)
#define WSTR 524    // f32 per point: 16 k * 32 w + 12 pad

#define FMA_ROW(c) \
  a##c##_0 += W0 * (f32x4)x##c; a##c##_1 += W1 * (f32x4)x##c; \
  a##c##_2 += W2 * (f32x4)x##c; a##c##_3 += W3 * (f32x4)x##c; \
  a##c##_4 += W4 * (f32x4)x##c; a##c##_5 += W5 * (f32x4)x##c; \
  a##c##_6 += W6 * (f32x4)x##c; a##c##_7 += W7 * (f32x4)x##c;

#define WRITE_C(ci, csval) \
  { size_t base = ((size_t)(csval)) * 64 + pl; \
    aq[base +  0] = make_uint4(pk2(a##ci##_0.x, a##ci##_0.y), pk2(a##ci##_0.z, a##ci##_0.w), \
                               pk2(a##ci##_1.x, a##ci##_1.y), pk2(a##ci##_1.z, a##ci##_1.w)); \
    aq[base + 16] = make_uint4(pk2(a##ci##_2.x, a##ci##_2.y), pk2(a##ci##_2.z, a##ci##_2.w), \
                               pk2(a##ci##_3.x, a##ci##_3.y), pk2(a##ci##_3.z, a##ci##_3.w)); \
    aq[base + 32] = make_uint4(pk2(a##ci##_4.x, a##ci##_4.y), pk2(a##ci##_4.z, a##ci##_4.w), \
                               pk2(a##ci##_5.x, a##ci##_5.y), pk2(a##ci##_5.z, a##ci##_5.w)); \
    aq[base + 48] = make_uint4(pk2(a##ci##_6.x, a##ci##_6.y), pk2(a##ci##_6.z, a##ci##_6.w), \
                               pk2(a##ci##_7.x, a##ci##_7.y), pk2(a##ci##_7.z, a##ci##_7.w)); }

__global__ __launch_bounds__(256, 2) void fused(const ushort* __restrict__ inT,
                                                const float4* __restrict__ pos4,
                                                const int* __restrict__ nn_idx,
                                                const float* __restrict__ dsbuf,
                                                const float* __restrict__ prm_g,
                                                const ushort* __restrict__ LTf,
                                                const float* __restrict__ lin_b,
                                                float* __restrict__ out) {
  __shared__ __align__(16) char smem[16 * XSTR + 16 * WSTR * 4];  // 70656 B
  __shared__ float prms[128];
  char* xraw = smem;
  float* wlds = (float*)(smem + 16 * XSTR);
  int t = threadIdx.x;
  int blk = blockIdx.x;          // 1024 tiles of 16 points
  int b = blk >> 8;
  int n0 = (blk & 255) << 4;
  if (t < 128) prms[t] = prm_g[t];
  __syncthreads();
  // ---- phase 1: stage. thread (k = t>>4, p = t&15) ----
  {
    int k = t >> 4, p = t & 15;
    int r = blk * 16 + p;
    int n = n0 + p;
    int j = nn_idx[(size_t)r * 16 + k];
    float4 pj = pos4[b * NPTS + j];
    float4 pn = pos4[b * NPTS + n];
    float lx = pj.x - pn.x, ly = pj.y - pn.y, lz = pj.z - pn.z;
    float ds = dsbuf[(size_t)r * 16 + k];
    const uint4* srcx = (const uint4*)(inT + ((size_t)(b * NPTS + j)) * 64);
    uint4* dstx = (uint4*)(xraw + p * XSTR + k * 144);
#pragma unroll
    for (int i = 0; i < 8; ++i) dstx[i] = srcx[i];
    float* wr = wlds + p * WSTR + k * 32;
#pragma unroll
    for (int w = 0; w < 32; ++w) {
      float v = fmaf(prms[w * 3], lx,
                fmaf(prms[w * 3 + 1], ly,
                fmaf(prms[w * 3 + 2], lz, prms[96 + w])));
      wr[w] = fmaxf(v, 0.f) * ds;
    }
  }
  __syncthreads();
  // ---- phase 2: feat in NAMED registers. thread (pl = t&15, cl = t>>4) ----
  int pl = t & 15, cl = t >> 4;
  f32x4 a0_0=(f32x4)0.f, a0_1=(f32x4)0.f, a0_2=(f32x4)0.f, a0_3=(f32x4)0.f,
        a0_4=(f32x4)0.f, a0_5=(f32x4)0.f, a0_6=(f32x4)0.f, a0_7=(f32x4)0.f;
  f32x4 a1_0=(f32x4)0.f, a1_1=(f32x4)0.f, a1_2=(f32x4)0.f, a1_3=(f32x4)0.f,
        a1_4=(f32x4)0.f, a1_5=(f32x4)0.f, a1_6=(f32x4)0.f, a1_7=(f32x4)0.f;
  f32x4 a2_0=(f32x4)0.f, a2_1=(f32x4)0.f, a2_2=(f32x4)0.f, a2_3=(f32x4)0.f,
        a2_4=(f32x4)0.f, a2_5=(f32x4)0.f, a2_6=(f32x4)0.f, a2_7=(f32x4)0.f;
  f32x4 a3_0=(f32x4)0.f, a3_1=(f32x4)0.f, a3_2=(f32x4)0.f, a3_3=(f32x4)0.f,
        a3_4=(f32x4)0.f, a3_5=(f32x4)0.f, a3_6=(f32x4)0.f, a3_7=(f32x4)0.f;
  {
    const char* xrow = xraw + pl * XSTR;
    const float* wp = wlds + pl * WSTR;
#pragma unroll 4
    for (int kk = 0; kk < 16; ++kk) {
      unsigned xa = *(const unsigned*)(xrow + kk * 144 + cl * 4);        // ch 2cl,2cl+1
      unsigned xb = *(const unsigned*)(xrow + kk * 144 + 64 + cl * 4);   // ch 32+2cl,33+2cl
      float x0 = __uint_as_float(xa << 16);
      float x1 = __uint_as_float(xa & 0xFFFF0000u);
      float x2 = __uint_as_float(xb << 16);
      float x3 = __uint_as_float(xb & 0xFFFF0000u);
      const f32x4* wk = (const f32x4*)(wp + kk * 32);
      f32x4 W0 = wk[0], W1 = wk[1], W2 = wk[2], W3 = wk[3];
      f32x4 W4 = wk[4], W5 = wk[5], W6 = wk[6], W7 = wk[7];
      FMA_ROW(0)
      FMA_ROW(1)
      FMA_ROW(2)
      FMA_ROW(3)
    }
  }
  __syncthreads();   // everyone done reading xraw/wlds
  // ---- phase 3: write A-frags (bf16) over the staging LDS (64 KB) ----
  uint4* aq = (uint4*)smem;
  WRITE_C(0, 2 * cl)
  WRITE_C(1, 2 * cl + 1)
  WRITE_C(2, 32 + 2 * cl)
  WRITE_C(3, 33 + 2 * cl)
  __syncthreads();
  // ---- phase 4: MFMA GEMM. wave wv owns output tile ot=wv, full K ----
  {
    int wv = t >> 6, l = t & 63;
    const uint4* Lq = (const uint4*)LTf;
    f32x4 cacc = (f32x4)0.f;
#pragma unroll 4
    for (int s = 0; s < 64; ++s) {
      uint4 ua = aq[s * 64 + l];
      uint4 ub = Lq[(s * 4 + wv) * 64 + l];
      bf16x8 A = *reinterpret_cast<bf16x8*>(&ua);
      bf16x8 B = *reinterpret_cast<bf16x8*>(&ub);
      cacc = __builtin_amdgcn_mfma_f32_16x16x32_bf16(A, B, cacc, 0, 0, 0);
    }
    int o = wv * 16 + (l & 15);
    float bias = lin_b[o];
    cacc.x += bias; cacc.y += bias; cacc.z += bias; cacc.w += bias;
    *(f32x4*)(out + ((size_t)(b * 64 + o)) * NPTS + n0 + (l >> 4) * 4) = cacc;
  }
}

// ------------------------------- launch ---------------------------------------
extern "C" void kernel_launch(void* const* d_in, const int* in_sizes, int n_in,
                              void* d_out, int out_size, void* d_ws, size_t ws_size,
                              hipStream_t stream) {
  (void)in_sizes; (void)n_in; (void)out_size; (void)ws_size;
  const float* inputs = (const float*)d_in[0];
  const float* pos    = (const float*)d_in[1];
  const float* invd   = (const float*)d_in[2];
  const float* wn_w   = (const float*)d_in[3];
  const float* wn_g   = (const float*)d_in[5];
  const float* wn_be  = (const float*)d_in[6];
  const float* dn_w1  = (const float*)d_in[7];
  const float* dn_g1  = (const float*)d_in[9];
  const float* dn_be1 = (const float*)d_in[10];
  const float* dn_w2  = (const float*)d_in[11];
  const float* dn_b2  = (const float*)d_in[12];
  const float* lin_w  = (const float*)d_in[13];
  const float* lin_b  = (const float*)d_in[14];
  float* outp = (float*)d_out;

  char* ws = (char*)d_ws;
  double* stats = (double*)ws;                         // 128 B
  float*  prm   = (float*)(ws + 1024);                 // 640 B
  float4* pos4  = (float4*)(ws + 4096);                // 256 KB
  int*    nnidx = (int*)(ws + (size_t)(1u << 19));     // 1 MB   [0.5, 1.5)
  float*  dsbuf = (float*)(ws + (size_t)(3u << 19));   // 1 MB   [1.5, 2.5)
  ushort* inT   = (ushort*)(ws + (size_t)(5u << 19));  // 2 MB   [2.5, 4.5)
  ushort* LTf   = (ushort*)(ws + (size_t)(9u << 19));  // 256 KB [4.5, 4.75)
  uint4*  keys  = (uint4*)(ws + (size_t)(5u << 20));   // 16 MB  [5, 21)

  hipMemsetAsync(stats, 0, 128, stream);
  pack_pos4<<<64, 256, 0, stream>>>(pos, pos4);
  transpose_in<<<256, 256, 0, stream>>>(inputs, inT);
  prep_LTf<<<64, 256, 0, stream>>>(lin_w, LTf);
  knn_partial<<<dim3(64, NCHUNK), 256, 0, stream>>>(pos4, keys);
  merge_stats<<<64, 256, 0, stream>>>(pos4, invd, keys, nnidx, dsbuf, stats);
  finalize_params<<<1, 64, 0, stream>>>(stats, wn_w, wn_g, wn_be, dn_w1, dn_g1, dn_be1, prm);
  ds_kernel<<<64, 256, 0, stream>>>(dsbuf, prm, dn_w2, dn_b2);
  fused<<<1024, 256, 0, stream>>>(inT, pos4, nnidx, dsbuf, prm, LTf, lin_b, outp);
}